// Round 9
// baseline (367.197 us; speedup 1.0000x reference)
//
#include <hip/hip_runtime.h>

#define BB 4
#define SLQ 1024
#define SLK 2048
#define EE 512
#define HH 8
#define HD 64

typedef unsigned short u16;
typedef __attribute__((ext_vector_type(8))) short s16x8;
typedef __attribute__((ext_vector_type(4))) float f32x4;

__device__ __forceinline__ float bf2f(u16 u) {
  union { unsigned int i; float f; } v; v.i = ((unsigned int)u) << 16; return v.f;
}
__device__ __forceinline__ u16 f2bf(float f) {
  union { float f; unsigned int i; } v; v.f = f;
  unsigned int i = v.i;
  return (u16)((i + 0x7fffu + ((i >> 16) & 1u)) >> 16);
}

__device__ __forceinline__ void async16(const u16* g, u16* l) {
  __builtin_amdgcn_global_load_lds(
      (const __attribute__((address_space(1))) unsigned int*)g,
      (__attribute__((address_space(3))) unsigned int*)l, 16, 0, 0);
}

// NT GEMM: C[m,n] = alpha*sum_k A[m,k]*B[n,k] + bias[n]
// MODE 0: row-major, per-wave barrier-free staged write
// MODE 1: head-split [B,H,Lsub,64] direct scatter
// SKIPQ 0: none; 1: b=z>>3, skip tileM>=qlen[b]; 2: b=tileM>>10 (Lsub=1024)
template<int BM, int BN, int MODE, int SKIPQ>
__global__ __launch_bounds__(256, (BM == 128 ? 4 : 6))
void gemm_nt(const u16* __restrict__ A, const u16* __restrict__ Bm,
             const float* __restrict__ bias, u16* __restrict__ C,
             int M, int N, int K, int lda, int ldb, int ldc,
             long sAz, long sBz, long sCz, float alpha, int Lsub,
             const int* __restrict__ qlen)
{
  constexpr int WTM = BM / 2, WTN = BN / 2;
  constexpr int MI = WTM / 16, NI = WTN / 16;
  constexpr int EPAD = WTN + 8;
  constexpr int SM1 = (BM + BN) * 32;
  constexpr int SM2 = (MODE == 0) ? 4 * WTM * EPAD : 0;
  constexpr int SM = (SM1 > SM2) ? SM1 : SM2;

  const int z = blockIdx.z;
  const int tileM = blockIdx.y * BM;
  const int tileN = blockIdx.x * BN;

  if (SKIPQ == 1) { if (tileM >= qlen[z >> 3]) return; }
  if (SKIPQ == 2) { int b = tileM >> 10; if ((tileM & 1023) >= qlen[b]) return; }

  __shared__ __align__(16) u16 smem[SM];
  u16* ldsA = smem;
  u16* ldsB = smem + BM * 32;

  const int t = threadIdx.x;
  const int lane = t & 63;
  const int wave = t >> 6;
  const int waveM = wave >> 1;
  const int waveN = wave & 1;
  const int lm = lane & 15;
  const int kg = lane >> 4;

  const u16* Ab = A + (long)z * sAz + (long)tileM * lda;
  const u16* Bb = Bm + (long)z * sBz + (long)tileN * ldb;

  f32x4 acc[MI][NI];
#pragma unroll
  for (int i = 0; i < MI; ++i)
#pragma unroll
    for (int j = 0; j < NI; ++j) acc[i][j] = (f32x4){0.f, 0.f, 0.f, 0.f};

  for (int kt = 0; kt < K; kt += 32) {
    __syncthreads();
#pragma unroll
    for (int i = 0; i < (BM * 4) / 256; ++i) {
      int c = i * 256 + t;
      async16(Ab + (long)(c >> 2) * lda + kt + (c & 3) * 8, ldsA + (c - lane) * 8);
    }
#pragma unroll
    for (int i = 0; i < (BN * 4) / 256; ++i) {
      int c = i * 256 + t;
      async16(Bb + (long)(c >> 2) * ldb + kt + (c & 3) * 8, ldsB + (c - lane) * 8);
    }
    __syncthreads();

    s16x8 aF[MI], bF[NI];
#pragma unroll
  for (int i = 0; i < MI; ++i)
      aF[i] = *(const s16x8*)&ldsA[(waveM * WTM + i * 16 + lm) * 32 + kg * 8];
#pragma unroll
    for (int j = 0; j < NI; ++j)
      bF[j] = *(const s16x8*)&ldsB[(waveN * WTN + j * 16 + lm) * 32 + kg * 8];
#pragma unroll
    for (int i = 0; i < MI; ++i)
#pragma unroll
      for (int j = 0; j < NI; ++j)
        acc[i][j] = __builtin_amdgcn_mfma_f32_16x16x32_bf16(aF[i], bF[j], acc[i][j], 0, 0, 0);
  }

  if (MODE == 0) {
    // per-wave staged write: no cross-wave barriers in the store phase
    u16* ep = smem + wave * (WTM * EPAD);
    __syncthreads();
#pragma unroll
    for (int i = 0; i < MI; ++i)
#pragma unroll
      for (int j = 0; j < NI; ++j) {
        int n = waveN * WTN + j * 16 + lm;
        float bv = bias ? bias[tileN + n] : 0.0f;
#pragma unroll
        for (int r = 0; r < 4; ++r)
          ep[(i * 16 + kg * 4 + r) * EPAD + j * 16 + lm] = f2bf(acc[i][j][r] * alpha + bv);
      }
    const long Crow = (long)z * sCz + (long)(tileM + waveM * WTM) * ldc + tileN + waveN * WTN;
#pragma unroll
    for (int it = 0; it < (WTM * WTN) / 512; ++it) {
      int idx = it * 64 + lane;
      int row = idx / (WTN / 8), seg = idx % (WTN / 8);
      *(uint4*)&C[Crow + (long)row * ldc + seg * 8] =
          *(const uint4*)&ep[row * EPAD + seg * 8];
    }
  } else {
#pragma unroll
    for (int j = 0; j < NI; ++j) {
      int n = tileN + waveN * WTN + j * 16 + lm;
      float bv = bias ? bias[n] : 0.0f;
#pragma unroll
      for (int i = 0; i < MI; ++i) {
#pragma unroll
        for (int r = 0; r < 4; ++r) {
          int m = tileM + waveM * WTM + i * 16 + kg * 4 + r;
          float v = acc[i][j][r] * alpha + bv;
          int b = m / Lsub, l = m - b * Lsub;
          int h = n >> 6, d = n & 63;
          C[(((long)(b * HH + h) * Lsub + l) << 6) + d] = f2bf(v);
        }
      }
    }
  }
}

// multi-projection: z selects weight/bias/output; z<NPROJ-1 -> head-split [B,H,L,64],
// z==NPROJ-1 -> transposed [B,H,64,L] staged write. K = EE, N = EE.
template<int BM, int BN, int SKIPQ, int NPROJ>
__global__ __launch_bounds__(256, 6)
void gemm_proj(const u16* __restrict__ A,
               const u16* B0, const u16* B1, const u16* B2,
               const float* bias0, const float* bias1, const float* bias2,
               u16* C0, u16* C1, u16* C2,
               int M, int lda, int Lsub, const int* __restrict__ qlen)
{
  constexpr int WTM = BM / 2, WTN = BN / 2;
  constexpr int MI = WTM / 16, NI = WTN / 16;

  const int z = blockIdx.z;
  const int tileM = blockIdx.y * BM;
  const int tileN = blockIdx.x * BN;
  if (SKIPQ == 2) { int b = tileM >> 10; if ((tileM & 1023) >= qlen[b]) return; }

  const u16* Bm = (z == 0) ? B0 : (z == 1) ? B1 : B2;
  const float* bias = (z == 0) ? bias0 : (z == 1) ? bias1 : bias2;
  u16* C = (z == 0) ? C0 : (z == 1) ? C1 : C2;
  const bool tr = (z == NPROJ - 1);

  __shared__ __align__(16) u16 smem[(BM + BN) * 32];
  u16* ldsA = smem;
  u16* ldsB = smem + BM * 32;

  const int t = threadIdx.x;
  const int lane = t & 63;
  const int wave = t >> 6;
  const int waveM = wave >> 1;
  const int waveN = wave & 1;
  const int lm = lane & 15;
  const int kg = lane >> 4;

  const u16* Ab = A + (long)tileM * lda;
  const u16* Bb = Bm + (long)tileN * EE;

  f32x4 acc[MI][NI];
#pragma unroll
  for (int i = 0; i < MI; ++i)
#pragma unroll
    for (int j = 0; j < NI; ++j) acc[i][j] = (f32x4){0.f, 0.f, 0.f, 0.f};

  for (int kt = 0; kt < EE; kt += 32) {
    __syncthreads();
#pragma unroll
    for (int i = 0; i < (BM * 4) / 256; ++i) {
      int c = i * 256 + t;
      async16(Ab + (long)(c >> 2) * lda + kt + (c & 3) * 8, ldsA + (c - lane) * 8);
    }
#pragma unroll
    for (int i = 0; i < (BN * 4) / 256; ++i) {
      int c = i * 256 + t;
      async16(Bb + (long)(c >> 2) * EE + kt + (c & 3) * 8, ldsB + (c - lane) * 8);
    }
    __syncthreads();

    s16x8 aF[MI], bF[NI];
#pragma unroll
    for (int i = 0; i < MI; ++i)
      aF[i] = *(const s16x8*)&ldsA[(waveM * WTM + i * 16 + lm) * 32 + kg * 8];
#pragma unroll
    for (int j = 0; j < NI; ++j)
      bF[j] = *(const s16x8*)&ldsB[(waveN * WTN + j * 16 + lm) * 32 + kg * 8];
#pragma unroll
    for (int i = 0; i < MI; ++i)
#pragma unroll
      for (int j = 0; j < NI; ++j)
        acc[i][j] = __builtin_amdgcn_mfma_f32_16x16x32_bf16(aF[i], bF[j], acc[i][j], 0, 0, 0);
  }

  if (!tr) {
#pragma unroll
    for (int j = 0; j < NI; ++j) {
      int n = tileN + waveN * WTN + j * 16 + lm;
      float bv = bias[n];
#pragma unroll
      for (int i = 0; i < MI; ++i)
#pragma unroll
        for (int r = 0; r < 4; ++r) {
          int m = tileM + waveM * WTM + i * 16 + kg * 4 + r;
          int b = m / Lsub, l = m - b * Lsub;
          int h = n >> 6, d = n & 63;
          C[(((long)(b * HH + h) * Lsub + l) << 6) + d] = f2bf(acc[i][j][r] + bv);
        }
    }
  } else {
    constexpr int PAD = BM + 8;
    const int bb = tileM / Lsub;
    const int l0 = tileM - bb * Lsub;
#pragma unroll
    for (int c = 0; c < BN / 32; ++c) {
      __syncthreads();
#pragma unroll
      for (int j = 0; j < NI; ++j) {
        int nloc = waveN * WTN + j * 16 + lm;
        if (nloc >= c * 32 && nloc < c * 32 + 32) {
          int nl = nloc - c * 32;
          float bv = bias[tileN + nloc];
#pragma unroll
          for (int i = 0; i < MI; ++i)
#pragma unroll
            for (int r = 0; r < 4; ++r) {
              int mm = waveM * WTM + i * 16 + kg * 4 + r;
              smem[nl * PAD + mm] = f2bf(acc[i][j][r] + bv);
            }
        }
      }
      __syncthreads();
#pragma unroll
      for (int v = 0; v < (32 * BM) / (256 * 8); ++v) {
        int idx = v * 256 + t;
        int nl = idx / (BM / 8), m8 = idx % (BM / 8);
        int n = tileN + c * 32 + nl;
        int h = n >> 6, d = n & 63;
        *(uint4*)&C[((long)(bb * HH + h) * HD + d) * Lsub + l0 + m8 * 8] =
            *(const uint4*)&smem[nl * PAD + m8 * 8];
      }
    }
  }
}

// cross flash attention: 128 q-rows x 512-key chunk per block (4 K-tiles, online
// softmax), two 64-q groups processed sequentially against the SAME staged K/V
// (doubles MFMA per barrier, halves staging traffic). SWAPPED QK^T; per-wave P
// buffer (no cross-wave sharing -> no extra barrier); tree reductions.
// 1-D grid 1024, XCD-swizzled; K/V prefetch double-buffer in NAMED registers.
__global__ __launch_bounds__(256, 3)
void cross_flash_chunk(const u16* __restrict__ Qc, const u16* __restrict__ Kc,
                       const u16* __restrict__ Vt, u16* __restrict__ Opart,
                       float2* __restrict__ ml, const int* __restrict__ qlen)
{
  const int lin = blockIdx.x;
  const int lid = (lin & 7) * 128 + (lin >> 3);   // bijective: 1024 % 8 == 0
  const int qt = lid & 7;               // 8 q-tiles of 128
  const int bh = (lid >> 3) & 31;       // 32
  const int ck = lid >> 8;              // 4 chunks of 512 keys
  const int b = bh >> 3;
  const int qn = qlen[b];
  if (qt * 128 >= qn) return;
  const bool doB = (qt * 128 + 64) < qn;   // block-uniform

  __shared__ __align__(16) u16 Kt[128 * 72];
  __shared__ __align__(16) u16 Vl[64 * 136];
  __shared__ __align__(16) u16 Pl[4 * 16 * 136];

  const int t = threadIdx.x, lane = t & 63, w = t >> 6;
  const int col = lane & 15, quad = lane >> 4;

  const u16* Qb = Qc + (long)bh * SLQ * HD;
  const u16* Kb = Kc + (long)bh * SLK * HD;
  const u16* Vb = Vt + (long)bh * HD * SLK;

  const int qA = qt * 128 + w * 16 + col;
  const int qB = qA + 64;                         // < SLQ always
  s16x8 aQA0 = *(const s16x8*)(Qb + (long)qA * HD + quad * 8);
  s16x8 aQA1 = *(const s16x8*)(Qb + (long)qA * HD + 32 + quad * 8);
  s16x8 aQB0 = *(const s16x8*)(Qb + (long)qB * HD + quad * 8);
  s16x8 aQB1 = *(const s16x8*)(Qb + (long)qB * HD + 32 + quad * 8);

  f32x4 OA[4], OB[4];
#pragma unroll
  for (int n = 0; n < 4; ++n) {
    OA[n] = (f32x4){0.f, 0.f, 0.f, 0.f};
    OB[n] = (f32x4){0.f, 0.f, 0.f, 0.f};
  }
  float mrA = -1e30f, lrA = 0.f, mrB = -1e30f, lrB = 0.f;

  u16* Pw = Pl + w * (16 * 136);

  const int krow = t >> 3, kcol = (t & 7) * 8;   // K stage: 128 rows x 64 cols
  const int vrow = t >> 4, vcol = (t & 15) * 8;  // V stage: 64 rows x 128 cols

  uint4 kr0, kr1, kr2, kr3, vr0, vr1, vr2, vr3;
  {
    const int kb = ck * 512;
    kr0 = *(const uint4*)(Kb + (long)(kb + krow) * HD + kcol);
    kr1 = *(const uint4*)(Kb + (long)(kb + krow + 32) * HD + kcol);
    kr2 = *(const uint4*)(Kb + (long)(kb + krow + 64) * HD + kcol);
    kr3 = *(const uint4*)(Kb + (long)(kb + krow + 96) * HD + kcol);
    vr0 = *(const uint4*)(Vb + (long)(vrow) * SLK + kb + vcol);
    vr1 = *(const uint4*)(Vb + (long)(vrow + 16) * SLK + kb + vcol);
    vr2 = *(const uint4*)(Vb + (long)(vrow + 32) * SLK + kb + vcol);
    vr3 = *(const uint4*)(Vb + (long)(vrow + 48) * SLK + kb + vcol);
  }

#pragma unroll 1
  for (int kt = 0; kt < 4; ++kt) {
    __syncthreads();                    // prev tile's LDS reads done
    *(uint4*)&Kt[(krow) * 72 + kcol] = kr0;
    *(uint4*)&Kt[(krow + 32) * 72 + kcol] = kr1;
    *(uint4*)&Kt[(krow + 64) * 72 + kcol] = kr2;
    *(uint4*)&Kt[(krow + 96) * 72 + kcol] = kr3;
    *(uint4*)&Vl[(vrow) * 136 + vcol] = vr0;
    *(uint4*)&Vl[(vrow + 16) * 136 + vcol] = vr1;
    *(uint4*)&Vl[(vrow + 32) * 136 + vcol] = vr2;
    *(uint4*)&Vl[(vrow + 48) * 136 + vcol] = vr3;
    if (kt < 3) {
      const int kb = ck * 512 + (kt + 1) * 128;
      kr0 = *(const uint4*)(Kb + (long)(kb + krow) * HD + kcol);
      kr1 = *(const uint4*)(Kb + (long)(kb + krow + 32) * HD + kcol);
      kr2 = *(const uint4*)(Kb + (long)(kb + krow + 64) * HD + kcol);
      kr3 = *(const uint4*)(Kb + (long)(kb + krow + 96) * HD + kcol);
      vr0 = *(const uint4*)(Vb + (long)(vrow) * SLK + kb + vcol);
      vr1 = *(const uint4*)(Vb + (long)(vrow + 16) * SLK + kb + vcol);
      vr2 = *(const uint4*)(Vb + (long)(vrow + 32) * SLK + kb + vcol);
      vr3 = *(const uint4*)(Vb + (long)(vrow + 48) * SLK + kb + vcol);
    }
    __syncthreads();                    // tile visible

#pragma unroll 1
    for (int g = 0; g < 2; ++g) {
      if (g == 1 && !doB) break;        // block-uniform
      const s16x8 aQ0 = (g == 0) ? aQA0 : aQB0;
      const s16x8 aQ1 = (g == 0) ? aQA1 : aQB1;
      float mr = (g == 0) ? mrA : mrB;
      float lr = (g == 0) ? lrA : lrB;

      // s[j][r] = S[k = j*16 + quad*4 + r][q = col]   (swapped operands)
      f32x4 s[8];
#pragma unroll
      for (int j = 0; j < 8; ++j) s[j] = (f32x4){0.f, 0.f, 0.f, 0.f};
#pragma unroll
      for (int j = 0; j < 8; ++j) {
        s16x8 bK0 = *(const s16x8*)&Kt[(j * 16 + col) * 72 + quad * 8];
        s16x8 bK1 = *(const s16x8*)&Kt[(j * 16 + col) * 72 + 32 + quad * 8];
        s[j] = __builtin_amdgcn_mfma_f32_16x16x32_bf16(bK0, aQ0, s[j], 0, 0, 0);
        s[j] = __builtin_amdgcn_mfma_f32_16x16x32_bf16(bK1, aQ1, s[j], 0, 0, 0);
      }
#pragma unroll
      for (int j = 0; j < 8; ++j)
#pragma unroll
        for (int r = 0; r < 4; ++r)
          s[j][r] *= 0.125f;

      float mj[8];
#pragma unroll
      for (int j = 0; j < 8; ++j)
        mj[j] = fmaxf(fmaxf(s[j][0], s[j][1]), fmaxf(s[j][2], s[j][3]));
      float tm = fmaxf(fmaxf(fmaxf(mj[0], mj[1]), fmaxf(mj[2], mj[3])),
                       fmaxf(fmaxf(mj[4], mj[5]), fmaxf(mj[6], mj[7])));
      tm = fmaxf(tm, __shfl_xor(tm, 16));
      tm = fmaxf(tm, __shfl_xor(tm, 32));
      float mnew = fmaxf(mr, tm);
      float alpha = __expf(mr - mnew);
      mr = mnew;
      float psj[8];
#pragma unroll
      for (int j = 0; j < 8; ++j) {
        float p0 = __expf(s[j][0] - mnew);
        float p1 = __expf(s[j][1] - mnew);
        float p2 = __expf(s[j][2] - mnew);
        float p3 = __expf(s[j][3] - mnew);
        psj[j] = (p0 + p1) + (p2 + p3);
        unsigned int lo = (unsigned int)f2bf(p0) | ((unsigned int)f2bf(p1) << 16);
        unsigned int hi = (unsigned int)f2bf(p2) | ((unsigned int)f2bf(p3) << 16);
        *(uint2*)&Pw[col * 136 + j * 16 + quad * 4] = (uint2){lo, hi};
      }
      float ps = ((psj[0] + psj[1]) + (psj[2] + psj[3])) +
                 ((psj[4] + psj[5]) + (psj[6] + psj[7]));
      ps += __shfl_xor(ps, 16);
      ps += __shfl_xor(ps, 32);
      lr = lr * alpha + ps;

      float a0 = __shfl(alpha, quad * 4 + 0);
      float a1 = __shfl(alpha, quad * 4 + 1);
      float a2 = __shfl(alpha, quad * 4 + 2);
      float a3 = __shfl(alpha, quad * 4 + 3);
      if (g == 0) {
#pragma unroll
        for (int n = 0; n < 4; ++n) {
          OA[n][0] *= a0; OA[n][1] *= a1; OA[n][2] *= a2; OA[n][3] *= a3;
        }
#pragma unroll
        for (int kk = 0; kk < 4; ++kk) {
          s16x8 aP = *(const s16x8*)&Pw[col * 136 + kk * 32 + quad * 8];
#pragma unroll
          for (int n = 0; n < 4; ++n) {
            s16x8 bV = *(const s16x8*)&Vl[(n * 16 + col) * 136 + kk * 32 + quad * 8];
            OA[n] = __builtin_amdgcn_mfma_f32_16x16x32_bf16(aP, bV, OA[n], 0, 0, 0);
          }
        }
        mrA = mr; lrA = lr;
      } else {
#pragma unroll
        for (int n = 0; n < 4; ++n) {
          OB[n][0] *= a0; OB[n][1] *= a1; OB[n][2] *= a2; OB[n][3] *= a3;
        }
#pragma unroll
        for (int kk = 0; kk < 4; ++kk) {
          s16x8 aP = *(const s16x8*)&Pw[col * 136 + kk * 32 + quad * 8];
#pragma unroll
          for (int n = 0; n < 4; ++n) {
            s16x8 bV = *(const s16x8*)&Vl[(n * 16 + col) * 136 + kk * 32 + quad * 8];
            OB[n] = __builtin_amdgcn_mfma_f32_16x16x32_bf16(aP, bV, OB[n], 0, 0, 0);
          }
        }
        mrB = mr; lrB = lr;
      }
    }
  }

#pragma unroll
  for (int r = 0; r < 4; ++r) {
    int q = qt * 128 + w * 16 + quad * 4 + r;
    long gq = (long)bh * SLQ + q;
#pragma unroll
    for (int n = 0; n < 4; ++n)
      Opart[(gq * 4 + ck) * 64 + n * 16 + col] = f2bf(OA[n][r]);
  }
  if (quad == 0)
    ml[((long)bh * SLQ + qA) * 4 + ck] = (float2){mrA, lrA};
  if (doB) {
#pragma unroll
    for (int r = 0; r < 4; ++r) {
      int q = qt * 128 + 64 + w * 16 + quad * 4 + r;
      long gq = (long)bh * SLQ + q;
#pragma unroll
      for (int n = 0; n < 4; ++n)
        Opart[(gq * 4 + ck) * 64 + n * 16 + col] = f2bf(OB[n][r]);
    }
    if (quad == 0)
      ml[((long)bh * SLQ + qB) * 4 + ck] = (float2){mrB, lrB};
  }
}

// merge 4 cross chunks -> attn; also emit global (M, L) stats for the weights pass
__global__ __launch_bounds__(256)
void cross_combine(const u16* __restrict__ Opart, const float2* __restrict__ ml,
                   u16* __restrict__ attn, float2* __restrict__ stat,
                   const int* __restrict__ qlen)
{
  int gr = blockIdx.x * 16 + (threadIdx.x >> 4);
  int bh = gr >> 10, q = gr & 1023;
  int b = bh >> 3, h = bh & 7;
  if (q >= qlen[b]) return;
  int d = (threadIdx.x & 15) * 4;
  long base = (long)gr * 4;
  float M = -1e30f;
#pragma unroll
  for (int c = 0; c < 4; ++c) M = fmaxf(M, ml[base + c].x);
  float L = 0.f;
  float ax = 0.f, ay = 0.f, az = 0.f, aw = 0.f;
#pragma unroll
  for (int c = 0; c < 4; ++c) {
    float2 st = ml[base + c];
    float wgt = __expf(st.x - M);
    L += st.y * wgt;
    const u16* p = Opart + (base + c) * 64 + d;
    ax += bf2f(p[0]) * wgt; ay += bf2f(p[1]) * wgt;
    az += bf2f(p[2]) * wgt; aw += bf2f(p[3]) * wgt;
  }
  if (d == 0) stat[gr] = (float2){M, L};
  float inv = 1.0f / L;
  unsigned int lo = (unsigned int)f2bf(ax * inv) | ((unsigned int)f2bf(ay * inv) << 16);
  unsigned int hi = (unsigned int)f2bf(az * inv) | ((unsigned int)f2bf(aw * inv) << 16);
  *(uint2*)&attn[((long)b * SLQ + q) * EE + h * HD + d] = (uint2){lo, hi};
}

// head-mean attention weights by QK^T recompute.
// block = (key tile of 128, q tile of 64, b); K staged in LDS per head,
// software-pipelined over heads; wave owns 16 q rows x 128 keys.
__global__ __launch_bounds__(256, 4)
void wmean_recompute(const u16* __restrict__ Qc, const u16* __restrict__ Kc,
                     const float2* __restrict__ stat, float* __restrict__ outw,
                     const int* __restrict__ qlen)
{
  const int kt = blockIdx.x;             // 16 key tiles of 128
  const int qt = blockIdx.y;             // 16 q tiles of 64
  const int b  = blockIdx.z;             // 4
  const int qn = qlen[b];
  const int q0 = qt * 64;
  const int t = threadIdx.x, lane = t & 63, w = t >> 6;
  const int col = lane & 15, quad = lane >> 4;

  float* wr = outw + ((long)b * SLQ + q0) * SLK + kt * 128;

  if (q0 >= qn) {
    float4 z = {0.f, 0.f, 0.f, 0.f};
    for (int i = t; i < 64 * 32; i += 256) {
      int row = i >> 5, c = (i & 31) << 2;
      *(float4*)&wr[(long)row * SLK + c] = z;
    }
    return;
  }

  __shared__ __align__(16) u16 Kl[128 * 72];

  const int qw = q0 + w * 16;            // wave's 16 q rows
  const u16* Kbase = Kc + ((long)b * HH * SLK + (long)kt * 128) * HD;

  const int krow = t >> 3, kcol = (t & 7) * 8;

  // preload head 0's K tile into NAMED registers
  uint4 kr0, kr1, kr2, kr3;
  kr0 = *(const uint4*)(Kbase + (long)(krow) * HD + kcol);
  kr1 = *(const uint4*)(Kbase + (long)(krow + 32) * HD + kcol);
  kr2 = *(const uint4*)(Kbase + (long)(krow + 64) * HD + kcol);
  kr3 = *(const uint4*)(Kbase + (long)(krow + 96) * HD + kcol);

  f32x4 acc[8];
#pragma unroll
  for (int j = 0; j < 8; ++j) acc[j] = (f32x4){0.f, 0.f, 0.f, 0.f};

#pragma unroll 1
  for (int h = 0; h < 8; ++h) {
    const int bh = b * 8 + h;
    __syncthreads();                     // previous iteration's LDS reads done
    *(uint4*)&Kl[(krow) * 72 + kcol] = kr0;
    *(uint4*)&Kl[(krow + 32) * 72 + kcol] = kr1;
    *(uint4*)&Kl[(krow + 64) * 72 + kcol] = kr2;
    *(uint4*)&Kl[(krow + 96) * 72 + kcol] = kr3;
    if (h < 7) {
      const u16* Kn = Kbase + (long)(h + 1) * SLK * HD;
      kr0 = *(const uint4*)(Kn + (long)(krow) * HD + kcol);
      kr1 = *(const uint4*)(Kn + (long)(krow + 32) * HD + kcol);
      kr2 = *(const uint4*)(Kn + (long)(krow + 64) * HD + kcol);
      kr3 = *(const uint4*)(Kn + (long)(krow + 96) * HD + kcol);
    }
    const u16* Qb = Qc + ((long)bh * SLQ + qw) * HD;
    s16x8 aQ0 = *(const s16x8*)(Qb + col * HD + quad * 8);
    s16x8 aQ1 = *(const s16x8*)(Qb + col * HD + 32 + quad * 8);
    float m_[4], il_[4];
#pragma unroll
    for (int r = 0; r < 4; ++r) {
      float2 st = stat[(long)bh * SLQ + qw + quad * 4 + r];
      m_[r] = st.x; il_[r] = 0.125f / st.y;
    }
    __syncthreads();                     // K tile visible

    f32x4 s[8];
#pragma unroll
    for (int j = 0; j < 8; ++j) s[j] = (f32x4){0.f, 0.f, 0.f, 0.f};
#pragma unroll
    for (int j = 0; j < 8; ++j) {
      s16x8 bK0 = *(const s16x8*)&Kl[(j * 16 + col) * 72 + quad * 8];
      s16x8 bK1 = *(const s16x8*)&Kl[(j * 16 + col) * 72 + 32 + quad * 8];
      s[j] = __builtin_amdgcn_mfma_f32_16x16x32_bf16(aQ0, bK0, s[j], 0, 0, 0);
      s[j] = __builtin_amdgcn_mfma_f32_16x16x32_bf16(aQ1, bK1, s[j], 0, 0, 0);
    }
#pragma unroll
    for (int j = 0; j < 8; ++j)
#pragma unroll
      for (int r = 0; r < 4; ++r)
        acc[j][r] += __expf(s[j][r] * 0.125f - m_[r]) * il_[r];
  }

#pragma unroll
  for (int r = 0; r < 4; ++r) {
    int row = w * 16 + quad * 4 + r;
    bool v = (q0 + row) < qn;
#pragma unroll
    for (int j = 0; j < 8; ++j)
      wr[(long)row * SLK + j * 16 + col] = v ? acc[j][r] : 0.f;
  }
}

// self-attention: 128 q-rows x 256-key chunk per block (2 K-tiles, online softmax),
// two 64-q groups sequential against the same staged K/V. SWAPPED QK^T; per-wave P.
// 1-D grid 1024, XCD-swizzled; named-reg prefetch.
__global__ __launch_bounds__(256, 3)
void self_flash_chunk(const u16* __restrict__ Qc, const u16* __restrict__ Kc,
                      const u16* __restrict__ Vt, u16* __restrict__ Opart,
                      float2* __restrict__ ml, const int* __restrict__ qlen)
{
  const int lin = blockIdx.x;
  const int lid = (lin & 7) * 128 + (lin >> 3);   // bijective: 1024 % 8 == 0
  const int qt = lid & 7;                // 8 q-tiles of 128
  const int bh = (lid >> 3) & 31;
  const int ck = lid >> 8;               // 4 chunks of 256
  const int b = bh >> 3;
  const int kmax = qlen[b];
  if (qt * 128 >= kmax || ck * 256 >= kmax) return;
  const bool doB = (qt * 128 + 64) < kmax;   // block-uniform

  __shared__ __align__(16) u16 Kt[128 * 72];
  __shared__ __align__(16) u16 Vl[64 * 136];
  __shared__ __align__(16) u16 Pl[4 * 16 * 136];

  const int t = threadIdx.x, lane = t & 63, w = t >> 6;
  const int col = lane & 15, quad = lane >> 4;

  const u16* Qb = Qc + (long)bh * SLQ * HD;
  const u16* Kb = Kc + (long)bh * SLQ * HD;
  const u16* Vb = Vt + (long)bh * HD * SLQ;

  const int qA = qt * 128 + w * 16 + col;
  const int qB = qA + 64;                         // < SLQ always
  s16x8 aQA0 = *(const s16x8*)(Qb + (long)qA * HD + quad * 8);
  s16x8 aQA1 = *(const s16x8*)(Qb + (long)qA * HD + 32 + quad * 8);
  s16x8 aQB0 = *(const s16x8*)(Qb + (long)qB * HD + quad * 8);
  s16x8 aQB1 = *(const s16x8*)(Qb + (long)qB * HD + 32 + quad * 8);

  f32x4 OA[4], OB[4];
#pragma unroll
  for (int n = 0; n < 4; ++n) {
    OA[n] = (f32x4){0.f, 0.f, 0.f, 0.f};
    OB[n] = (f32x4){0.f, 0.f, 0.f, 0.f};
  }
  float mrA = -1e30f, lrA = 0.f, mrB = -1e30f, lrB = 0.f;

  u16* Pw = Pl + w * (16 * 136);

  const int krow = t >> 3, kcol = (t & 7) * 8;
  const int vrow = t >> 4, vcol = (t & 15) * 8;

  uint4 kr0, kr1, kr2, kr3, vr0, vr1, vr2, vr3;
  {
    const int kb = ck * 256;
    kr0 = *(const uint4*)(Kb + (long)(kb + krow) * HD + kcol);
    kr1 = *(const uint4*)(Kb + (long)(kb + krow + 32) * HD + kcol);
    kr2 = *(const uint4*)(Kb + (long)(kb + krow + 64) * HD + kcol);
    kr3 = *(const uint4*)(Kb + (long)(kb + krow + 96) * HD + kcol);
    vr0 = *(const uint4*)(Vb + (long)(vrow) * SLQ + kb + vcol);
    vr1 = *(const uint4*)(Vb + (long)(vrow + 16) * SLQ + kb + vcol);
    vr2 = *(const uint4*)(Vb + (long)(vrow + 32) * SLQ + kb + vcol);
    vr3 = *(const uint4*)(Vb + (long)(vrow + 48) * SLQ + kb + vcol);
  }

#pragma unroll 1
  for (int kt = 0; kt < 2; ++kt) {
    const int k0 = ck * 256 + kt * 128;
    if (k0 >= kmax) break;               // block-uniform
    __syncthreads();
    *(uint4*)&Kt[(krow) * 72 + kcol] = kr0;
    *(uint4*)&Kt[(krow + 32) * 72 + kcol] = kr1;
    *(uint4*)&Kt[(krow + 64) * 72 + kcol] = kr2;
    *(uint4*)&Kt[(krow + 96) * 72 + kcol] = kr3;
    *(uint4*)&Vl[(vrow) * 136 + vcol] = vr0;
    *(uint4*)&Vl[(vrow + 16) * 136 + vcol] = vr1;
    *(uint4*)&Vl[(vrow + 32) * 136 + vcol] = vr2;
    *(uint4*)&Vl[(vrow + 48) * 136 + vcol] = vr3;
    if (kt < 1) {
      const int kb = ck * 256 + 128;     // in-bounds (max 896+127 < 1024)
      kr0 = *(const uint4*)(Kb + (long)(kb + krow) * HD + kcol);
      kr1 = *(const uint4*)(Kb + (long)(kb + krow + 32) * HD + kcol);
      kr2 = *(const uint4*)(Kb + (long)(kb + krow + 64) * HD + kcol);
      kr3 = *(const uint4*)(Kb + (long)(kb + krow + 96) * HD + kcol);
      vr0 = *(const uint4*)(Vb + (long)(vrow) * SLQ + kb + vcol);
      vr1 = *(const uint4*)(Vb + (long)(vrow + 16) * SLQ + kb + vcol);
      vr2 = *(const uint4*)(Vb + (long)(vrow + 32) * SLQ + kb + vcol);
      vr3 = *(const uint4*)(Vb + (long)(vrow + 48) * SLQ + kb + vcol);
    }
    __syncthreads();

#pragma unroll 1
    for (int g = 0; g < 2; ++g) {
      if (g == 1 && !doB) break;        // block-uniform
      const s16x8 aQ0 = (g == 0) ? aQA0 : aQB0;
      const s16x8 aQ1 = (g == 0) ? aQA1 : aQB1;
      float mr = (g == 0) ? mrA : mrB;
      float lr = (g == 0) ? lrA : lrB;

      f32x4 s[8];
#pragma unroll
      for (int j = 0; j < 8; ++j) s[j] = (f32x4){0.f, 0.f, 0.f, 0.f};
#pragma unroll
      for (int j = 0; j < 8; ++j) {
        s16x8 bK0 = *(const s16x8*)&Kt[(j * 16 + col) * 72 + quad * 8];
        s16x8 bK1 = *(const s16x8*)&Kt[(j * 16 + col) * 72 + 32 + quad * 8];
        s[j] = __builtin_amdgcn_mfma_f32_16x16x32_bf16(bK0, aQ0, s[j], 0, 0, 0);
        s[j] = __builtin_amdgcn_mfma_f32_16x16x32_bf16(bK1, aQ1, s[j], 0, 0, 0);
      }
#pragma unroll
      for (int j = 0; j < 8; ++j)
#pragma unroll
        for (int r = 0; r < 4; ++r) {
          bool ok = (k0 + j * 16 + quad * 4 + r) < kmax;
          s[j][r] = ok ? s[j][r] * 0.125f : -1e30f;
        }

      float mj[8];
#pragma unroll
      for (int j = 0; j < 8; ++j)
        mj[j] = fmaxf(fmaxf(s[j][0], s[j][1]), fmaxf(s[j][2], s[j][3]));
      float tm = fmaxf(fmaxf(fmaxf(mj[0], mj[1]), fmaxf(mj[2], mj[3])),
                       fmaxf(fmaxf(mj[4], mj[5]), fmaxf(mj[6], mj[7])));
      tm = fmaxf(tm, __shfl_xor(tm, 16));
      tm = fmaxf(tm, __shfl_xor(tm, 32));
      float mnew = fmaxf(mr, tm);
      float alpha = __expf(mr - mnew);
      mr = mnew;
      float psj[8];
#pragma unroll
      for (int j = 0; j < 8; ++j) {
        float p0 = __expf(s[j][0] - mnew);
        float p1 = __expf(s[j][1] - mnew);
        float p2 = __expf(s[j][2] - mnew);
        float p3 = __expf(s[j][3] - mnew);
        psj[j] = (p0 + p1) + (p2 + p3);
        unsigned int lo = (unsigned int)f2bf(p0) | ((unsigned int)f2bf(p1) << 16);
        unsigned int hi = (unsigned int)f2bf(p2) | ((unsigned int)f2bf(p3) << 16);
        *(uint2*)&Pw[col * 136 + j * 16 + quad * 4] = (uint2){lo, hi};
      }
      float ps = ((psj[0] + psj[1]) + (psj[2] + psj[3])) +
                 ((psj[4] + psj[5]) + (psj[6] + psj[7]));
      ps += __shfl_xor(ps, 16);
      ps += __shfl_xor(ps, 32);
      lr = lr * alpha + ps;

      float a0 = __shfl(alpha, quad * 4 + 0);
      float a1 = __shfl(alpha, quad * 4 + 1);
      float a2 = __shfl(alpha, quad * 4 + 2);
      float a3 = __shfl(alpha, quad * 4 + 3);
      if (g == 0) {
#pragma unroll
        for (int n = 0; n < 4; ++n) {
          OA[n][0] *= a0; OA[n][1] *= a1; OA[n][2] *= a2; OA[n][3] *= a3;
        }
#pragma unroll
        for (int kk = 0; kk < 4; ++kk) {
          s16x8 aP = *(const s16x8*)&Pw[col * 136 + kk * 32 + quad * 8];
#pragma unroll
          for (int n = 0; n < 4; ++n) {
            s16x8 bV = *(const s16x8*)&Vl[(n * 16 + col) * 136 + kk * 32 + quad * 8];
            OA[n] = __builtin_amdgcn_mfma_f32_16x16x32_bf16(aP, bV, OA[n], 0, 0, 0);
          }
        }
        mrA = mr; lrA = lr;
      } else {
#pragma unroll
        for (int n = 0; n < 4; ++n) {
          OB[n][0] *= a0; OB[n][1] *= a1; OB[n][2] *= a2; OB[n][3] *= a3;
        }
#pragma unroll
        for (int kk = 0; kk < 4; ++kk) {
          s16x8 aP = *(const s16x8*)&Pw[col * 136 + kk * 32 + quad * 8];
#pragma unroll
          for (int n = 0; n < 4; ++n) {
            s16x8 bV = *(const s16x8*)&Vl[(n * 16 + col) * 136 + kk * 32 + quad * 8];
            OB[n] = __builtin_amdgcn_mfma_f32_16x16x32_bf16(aP, bV, OB[n], 0, 0, 0);
          }
        }
        mrB = mr; lrB = lr;
      }
    }
  }

#pragma unroll
  for (int r = 0; r < 4; ++r) {
    int q = qt * 128 + w * 16 + quad * 4 + r;
    long gq = (long)bh * SLQ + q;
#pragma unroll
    for (int n = 0; n < 4; ++n)
      Opart[(gq * 4 + ck) * 64 + n * 16 + col] = f2bf(OA[n][r]);
  }
  if (quad == 0)
    ml[((long)bh * SLQ + qA) * 4 + ck] = (float2){mrA, lrA};
  if (doB) {
#pragma unroll
    for (int r = 0; r < 4; ++r) {
      int q = qt * 128 + 64 + w * 16 + quad * 4 + r;
      long gq = (long)bh * SLQ + q;
#pragma unroll
      for (int n = 0; n < 4; ++n)
        Opart[(gq * 4 + ck) * 64 + n * 16 + col] = f2bf(OB[n][r]);
    }
    if (quad == 0)
      ml[((long)bh * SLQ + qB) * 4 + ck] = (float2){mrB, lrB};
  }
}

__global__ __launch_bounds__(256)
void self_combine(const u16* __restrict__ Opart, const float2* __restrict__ ml,
                  u16* __restrict__ attn, const int* __restrict__ qlen)
{
  int gr = blockIdx.x * 16 + (threadIdx.x >> 4);
  int bh = gr >> 10, q = gr & 1023;
  int b = bh >> 3, h = bh & 7;
  int kmax = qlen[b];
  if (q >= kmax) return;
  int NC = (kmax + 255) >> 8;
  int d = (threadIdx.x & 15) * 4;
  long base = (long)gr * 4;
  float M = -1e30f;
  for (int c = 0; c < NC; ++c) M = fmaxf(M, ml[base + c].x);
  float L = 0.f;
  float ax = 0.f, ay = 0.f, az = 0.f, aw = 0.f;
  for (int c = 0; c < NC; ++c) {
    float2 st = ml[base + c];
    float wgt = __expf(st.x - M);
    L += st.y * wgt;
    const u16* p = Opart + (base + c) * 64 + d;
    ax += bf2f(p[0]) * wgt; ay += bf2f(p[1]) * wgt;
    az += bf2f(p[2]) * wgt; aw += bf2f(p[3]) * wgt;
  }
  float inv = 1.0f / L;
  unsigned int lo = (unsigned int)f2bf(ax * inv) | ((unsigned int)f2bf(ay * inv) << 16);
  unsigned int hi = (unsigned int)f2bf(az * inv) | ((unsigned int)f2bf(aw * inv) << 16);
  *(uint2*)&attn[((long)b * SLQ + q) * EE + h * HD + d] = (uint2){lo, hi};
}

// fused input conversion: masked queries + keys + 9 weight matrices
__global__ __launch_bounds__(256)
void cvt_all(const float* __restrict__ queries, const float* __restrict__ keys,
             const int* __restrict__ qlen,
             const float* w0, const float* w1, const float* w2, const float* w3,
             const float* w4, const float* w5, const float* w6, const float* w7,
             const float* w8,
             u16* __restrict__ q0, u16* __restrict__ keysb, u16* __restrict__ Wb) {
  int blk = blockIdx.x;
  int t = threadIdx.x;
  const float* src;
  u16* dst;
  long off;
  bool mask = false;
  int b = 0, q = 0;
  if (blk < 1024) {
    off = (long)blk * 2048 + t * 8;
    int row = (int)(off >> 9);
    b = row >> 10; q = row & 1023;
    mask = true;
    src = queries; dst = q0;
  } else if (blk < 3072) {
    off = (long)(blk - 1024) * 2048 + t * 8;
    src = keys; dst = keysb;
  } else {
    int mat = (blk - 3072) >> 7, part = (blk - 3072) & 127;
    const float* srcs[9] = {w0, w1, w2, w3, w4, w5, w6, w7, w8};
    src = srcs[mat];
    off = (long)part * 2048 + t * 8;
    dst = Wb + (long)mat * EE * EE;
  }
  s16x8 o = (s16x8){0, 0, 0, 0, 0, 0, 0, 0};
  if (!mask || q < qlen[b]) {
    float4 a = *(const float4*)&src[off];
    float4 c = *(const float4*)&src[off + 4];
    o[0] = (short)f2bf(a.x); o[1] = (short)f2bf(a.y);
    o[2] = (short)f2bf(a.z); o[3] = (short)f2bf(a.w);
    o[4] = (short)f2bf(c.x); o[5] = (short)f2bf(c.y);
    o[6] = (short)f2bf(c.z); o[7] = (short)f2bf(c.w);
  }
  *(s16x8*)&dst[off] = o;
}

__device__ __forceinline__ float blockSum(float v, float* red4) {
#pragma unroll
  for (int o = 32; o; o >>= 1) v += __shfl_xor(v, o);
  if ((threadIdx.x & 63) == 0) red4[threadIdx.x >> 6] = v;
  __syncthreads();
  v = red4[0] + red4[1] + red4[2] + red4[3];
  __syncthreads();
  return v;
}

template<int OUTF32>
__global__ __launch_bounds__(256)
void silu_ln_kernel(const u16* __restrict__ x1, const u16* __restrict__ x2,
                    const float* __restrict__ g, const float* __restrict__ beta,
                    const int* __restrict__ qlen, void* __restrict__ outv, int mode) {
  int row = blockIdx.x;
  int b = row >> 10, q = row & 1023;
  int t = threadIdx.x;
  if (mode && q >= qlen[b]) {
    if (mode == 1) {
      if (OUTF32) {
        float* o = (float*)outv + (long)row * EE;
        o[2 * t] = 0.f; o[2 * t + 1] = 0.f;
      } else {
        u16* o = (u16*)outv + (long)row * EE;
        *(unsigned int*)&o[2 * t] = 0u;
      }
    }
    return;
  }
  __shared__ float red4[4];
  const u16* p1 = x1 + (long)row * EE;
  const u16* p2 = x2 + (long)row * EE;
  float a0 = bf2f(p1[2 * t]) + bf2f(p2[2 * t]);
  float a1 = bf2f(p1[2 * t + 1]) + bf2f(p2[2 * t + 1]);
  a0 = a0 / (1.f + __expf(-a0));
  a1 = a1 / (1.f + __expf(-a1));
  float mu = blockSum(a0 + a1, red4) * (1.f / 512.f);
  float d0 = a0 - mu, d1 = a1 - mu;
  float var = blockSum(d0 * d0 + d1 * d1, red4) * (1.f / 512.f);
  float rs = rsqrtf(var + 1e-5f);
  float r0 = d0 * rs * g[2 * t] + beta[2 * t];
  float r1 = d1 * rs * g[2 * t + 1] + beta[2 * t + 1];
  if (OUTF32) {
    float* o = (float*)outv + (long)row * EE;
    o[2 * t] = r0; o[2 * t + 1] = r1;
  } else {
    u16* o = (u16*)outv + (long)row * EE;
    o[2 * t] = f2bf(r0); o[2 * t + 1] = f2bf(r1);
  }
}

extern "C" void kernel_launch(void* const* d_in, const int* in_sizes, int n_in,
                              void* d_out, int out_size, void* d_ws, size_t ws_size,
                              hipStream_t stream) {
  const float* queries = (const float*)d_in[0];
  const float* keys    = (const float*)d_in[1];
  const int*   qlen    = (const int*)d_in[2];
  const float* cWq = (const float*)d_in[3],  *cbq = (const float*)d_in[4];
  const float* cWk = (const float*)d_in[5],  *cbk = (const float*)d_in[6];
  const float* cWv = (const float*)d_in[7],  *cbv = (const float*)d_in[8];
  const float* cWo = (const float*)d_in[9],  *cbo = (const float*)d_in[10];
  const float* sWq = (const float*)d_in[11], *sbq = (const float*)d_in[12];
  const float* sWk = (const float*)d_in[13], *sbk = (const float*)d_in[14];
  const float* sWv = (const float*)d_in[15], *sbv = (const float*)d_in[16];
  const float* sWo = (const float*)d_in[17], *sbo = (const float*)d_in[18];
  const float* Wf  = (const float*)d_in[19], *bfb = (const float*)d_in[20];
  const float* g_cross = (const float*)d_in[21], *b_cross = (const float*)d_in[22];
  const float* g_ffn   = (const float*)d_in[23], *b_ffn   = (const float*)d_in[24];
  const float* g_self  = (const float*)d_in[25], *b_self  = (const float*)d_in[26];

  float* out_q = (float*)d_out;
  float* out_w = out_q + (long)BB * SLQ * EE;

  u16* ws = (u16*)d_ws;
  u16* S     = ws;                               // region kept for layout; cross S no longer materialized
  u16* Qc    = S   + (long)BB * HH * SLQ * SLK;
  u16* Kc    = Qc  + (long)BB * HH * SLQ * HD;
  u16* Vt    = Kc  + (long)BB * HH * SLK * HD;
  u16* q0    = Vt  + (long)BB * HH * SLK * HD;
  u16* keysb = q0  + (long)BB * SLQ * EE;
  u16* attn  = keysb + (long)BB * SLK * EE;
  u16* proj  = attn + (long)BB * SLQ * EE;
  u16* q1    = proj + (long)BB * SLQ * EE;
  u16* fbuf  = q1  + (long)BB * SLQ * EE;
  u16* q2    = fbuf + (long)BB * SLQ * EE;
  u16* Wb    = q2  + (long)BB * SLQ * EE;
  const long WSLOT = (long)EE * EE;
  u16*    Cpb  = Wb + 9 * WSLOT;                  // cross O partials bf16: 32768*4*64
  float2* stat = (float2*)(Cpb + 8388608);        // 32768 float2 (M, L)

  // cross flash ml lives in the (now dead) S region, clear of the self overlay below
  float2* mlC = (float2*)(S + 33554432);          // 32768*4 float2

  // self partials overlay S (front of region)
  u16*    OpS = S;                                // 32768*4*64 bf16
  float2* mlS = (float2*)(S + 8388608);           // 32768*4 float2

  u16* bWq = Wb + 0 * WSLOT; u16* bWk = Wb + 1 * WSLOT; u16* bWv = Wb + 2 * WSLOT;
  u16* bWo = Wb + 3 * WSLOT; u16* bsWq = Wb + 4 * WSLOT; u16* bsWk = Wb + 5 * WSLOT;
  u16* bsWv = Wb + 6 * WSLOT; u16* bsWo = Wb + 7 * WSLOT; u16* bWf = Wb + 8 * WSLOT;

  dim3 blk(256);
  const int MQ = BB * SLQ;   // 4096
  const int MK = BB * SLK;   // 8192

  cvt_all<<<dim3(3072 + 9 * 128), blk, 0, stream>>>(
      queries, keys, qlen, cWq, cWk, cWv, cWo, sWq, sWk, sWv, sWo, Wf, q0, keysb, Wb);

  // cross Q projection
  gemm_nt<64, 64, 1, 2><<<dim3(EE / 64, MQ / 64, 1), blk, 0, stream>>>(
      q0, bWq, cbq, Qc, MQ, EE, EE, EE, EE, 0, 0, 0, 0, 1.0f, SLQ, qlen);
  // cross K+V projections in one dispatch
  gemm_proj<64, 64, 0, 2><<<dim3(EE / 64, MK / 64, 2), blk, 0, stream>>>(
      keysb, bWk, bWv, nullptr, cbk, cbv, nullptr, Kc, Vt, nullptr, MK, EE, SLK, qlen);

  // fused cross attention: no S materialization (1-D swizzled grid, 128 q/block)
  cross_flash_chunk<<<dim3(1024), blk, 0, stream>>>(Qc, Kc, Vt, Cpb, mlC, qlen);
  cross_combine<<<dim3(2048), blk, 0, stream>>>(Cpb, mlC, attn, stat, qlen);
  // head-mean attention weights via QK^T recompute (LDS-staged, head-pipelined)
  wmean_recompute<<<dim3(16, 16, BB), blk, 0, stream>>>(Qc, Kc, stat, out_w, qlen);

  gemm_nt<64, 64, 0, 2><<<dim3(EE / 64, MQ / 64, 1), blk, 0, stream>>>(
      attn, bWo, cbo, proj, MQ, EE, EE, EE, EE, EE, 0, 0, 0, 1.0f, SLQ, qlen);

  silu_ln_kernel<0><<<dim3(MQ), blk, 0, stream>>>(proj, q0, g_cross, b_cross, qlen, q1, 2);

  gemm_nt<64, 64, 0, 2><<<dim3(EE / 64, MQ / 64, 1), blk, 0, stream>>>(
      q1, bWf, bfb, fbuf, MQ, EE, EE, EE, EE, EE, 0, 0, 0, 1.0f, SLQ, qlen);

  silu_ln_kernel<0><<<dim3(MQ), blk, 0, stream>>>(q1, fbuf, g_ffn, b_ffn, qlen, q2, 1);

  // self Q/K/V projections in one dispatch
  gemm_proj<64, 64, 2, 3><<<dim3(EE / 64, MQ / 64, 3), blk, 0, stream>>>(
      q2, bsWq, bsWk, bsWv, sbq, sbk, sbv, Qc, Kc, Vt, MQ, EE, SLQ, qlen);

  // fused self attention (partials overlay S; 1-D swizzled grid, 128 q/block)
  self_flash_chunk<<<dim3(1024), blk, 0, stream>>>(Qc, Kc, Vt, OpS, mlS, qlen);
  self_combine<<<dim3(2048), blk, 0, stream>>>(OpS, mlS, attn, qlen);

  gemm_nt<64, 64, 0, 2><<<dim3(EE / 64, MQ / 64, 1), blk, 0, stream>>>(
      attn, bsWo, sbo, proj, MQ, EE, EE, EE, EE, EE, 0, 0, 0, 1.0f, SLQ, qlen);

  silu_ln_kernel<1><<<dim3(MQ), blk, 0, stream>>>(q2, proj, g_self, b_self, qlen, out_q, 1);
}

// Round 10
// 314.307 us; speedup vs baseline: 1.1683x; 1.1683x over previous
//
#include <hip/hip_runtime.h>

#define BB 4
#define SLQ 1024
#define SLK 2048
#define EE 512
#define HH 8
#define HD 64

typedef unsigned short u16;
typedef __attribute__((ext_vector_type(8))) short s16x8;
typedef __attribute__((ext_vector_type(4))) float f32x4;

__device__ __forceinline__ float bf2f(u16 u) {
  union { unsigned int i; float f; } v; v.i = ((unsigned int)u) << 16; return v.f;
}
__device__ __forceinline__ u16 f2bf(float f) {
  union { float f; unsigned int i; } v; v.f = f;
  unsigned int i = v.i;
  return (u16)((i + 0x7fffu + ((i >> 16) & 1u)) >> 16);
}

__device__ __forceinline__ void async16(const u16* g, u16* l) {
  __builtin_amdgcn_global_load_lds(
      (const __attribute__((address_space(1))) unsigned int*)g,
      (__attribute__((address_space(3))) unsigned int*)l, 16, 0, 0);
}

// NT GEMM: C[m,n] = alpha*sum_k A[m,k]*B[n,k] + bias[n]
// MODE 0: row-major, per-wave barrier-free staged write
// MODE 1: head-split [B,H,Lsub,64] direct scatter
// SKIPQ 0: none; 1: b=z>>3, skip tileM>=qlen[b]; 2: b=tileM>>10 (Lsub=1024)
template<int BM, int BN, int MODE, int SKIPQ>
__global__ __launch_bounds__(256, (BM == 128 ? 4 : 6))
void gemm_nt(const u16* __restrict__ A, const u16* __restrict__ Bm,
             const float* __restrict__ bias, u16* __restrict__ C,
             int M, int N, int K, int lda, int ldb, int ldc,
             long sAz, long sBz, long sCz, float alpha, int Lsub,
             const int* __restrict__ qlen)
{
  constexpr int WTM = BM / 2, WTN = BN / 2;
  constexpr int MI = WTM / 16, NI = WTN / 16;
  constexpr int EPAD = WTN + 8;
  constexpr int SM1 = (BM + BN) * 32;
  constexpr int SM2 = (MODE == 0) ? 4 * WTM * EPAD : 0;
  constexpr int SM = (SM1 > SM2) ? SM1 : SM2;

  const int z = blockIdx.z;
  const int tileM = blockIdx.y * BM;
  const int tileN = blockIdx.x * BN;

  if (SKIPQ == 1) { if (tileM >= qlen[z >> 3]) return; }
  if (SKIPQ == 2) { int b = tileM >> 10; if ((tileM & 1023) >= qlen[b]) return; }

  __shared__ __align__(16) u16 smem[SM];
  u16* ldsA = smem;
  u16* ldsB = smem + BM * 32;

  const int t = threadIdx.x;
  const int lane = t & 63;
  const int wave = t >> 6;
  const int waveM = wave >> 1;
  const int waveN = wave & 1;
  const int lm = lane & 15;
  const int kg = lane >> 4;

  const u16* Ab = A + (long)z * sAz + (long)tileM * lda;
  const u16* Bb = Bm + (long)z * sBz + (long)tileN * ldb;

  f32x4 acc[MI][NI];
#pragma unroll
  for (int i = 0; i < MI; ++i)
#pragma unroll
    for (int j = 0; j < NI; ++j) acc[i][j] = (f32x4){0.f, 0.f, 0.f, 0.f};

  for (int kt = 0; kt < K; kt += 32) {
    __syncthreads();
#pragma unroll
    for (int i = 0; i < (BM * 4) / 256; ++i) {
      int c = i * 256 + t;
      async16(Ab + (long)(c >> 2) * lda + kt + (c & 3) * 8, ldsA + (c - lane) * 8);
    }
#pragma unroll
    for (int i = 0; i < (BN * 4) / 256; ++i) {
      int c = i * 256 + t;
      async16(Bb + (long)(c >> 2) * ldb + kt + (c & 3) * 8, ldsB + (c - lane) * 8);
    }
    __syncthreads();

    s16x8 aF[MI], bF[NI];
#pragma unroll
    for (int i = 0; i < MI; ++i)
      aF[i] = *(const s16x8*)&ldsA[(waveM * WTM + i * 16 + lm) * 32 + kg * 8];
#pragma unroll
    for (int j = 0; j < NI; ++j)
      bF[j] = *(const s16x8*)&ldsB[(waveN * WTN + j * 16 + lm) * 32 + kg * 8];
#pragma unroll
    for (int i = 0; i < MI; ++i)
#pragma unroll
      for (int j = 0; j < NI; ++j)
        acc[i][j] = __builtin_amdgcn_mfma_f32_16x16x32_bf16(aF[i], bF[j], acc[i][j], 0, 0, 0);
  }

  if (MODE == 0) {
    // per-wave staged write: no cross-wave barriers in the store phase
    u16* ep = smem + wave * (WTM * EPAD);
    __syncthreads();
#pragma unroll
    for (int i = 0; i < MI; ++i)
#pragma unroll
      for (int j = 0; j < NI; ++j) {
        int n = waveN * WTN + j * 16 + lm;
        float bv = bias ? bias[tileN + n] : 0.0f;
#pragma unroll
        for (int r = 0; r < 4; ++r)
          ep[(i * 16 + kg * 4 + r) * EPAD + j * 16 + lm] = f2bf(acc[i][j][r] * alpha + bv);
      }
    const long Crow = (long)z * sCz + (long)(tileM + waveM * WTM) * ldc + tileN + waveN * WTN;
#pragma unroll
    for (int it = 0; it < (WTM * WTN) / 512; ++it) {
      int idx = it * 64 + lane;
      int row = idx / (WTN / 8), seg = idx % (WTN / 8);
      *(uint4*)&C[Crow + (long)row * ldc + seg * 8] =
          *(const uint4*)&ep[row * EPAD + seg * 8];
    }
  } else {
#pragma unroll
    for (int j = 0; j < NI; ++j) {
      int n = tileN + waveN * WTN + j * 16 + lm;
      float bv = bias ? bias[n] : 0.0f;
#pragma unroll
      for (int i = 0; i < MI; ++i) {
#pragma unroll
        for (int r = 0; r < 4; ++r) {
          int m = tileM + waveM * WTM + i * 16 + kg * 4 + r;
          float v = acc[i][j][r] * alpha + bv;
          int b = m / Lsub, l = m - b * Lsub;
          int h = n >> 6, d = n & 63;
          C[(((long)(b * HH + h) * Lsub + l) << 6) + d] = f2bf(v);
        }
      }
    }
  }
}

// multi-projection: z selects weight/bias/output; z<NPROJ-1 -> head-split [B,H,L,64],
// z==NPROJ-1 -> transposed [B,H,64,L] staged write. K = EE, N = EE.
template<int BM, int BN, int SKIPQ, int NPROJ>
__global__ __launch_bounds__(256, 6)
void gemm_proj(const u16* __restrict__ A,
               const u16* B0, const u16* B1, const u16* B2,
               const float* bias0, const float* bias1, const float* bias2,
               u16* C0, u16* C1, u16* C2,
               int M, int lda, int Lsub, const int* __restrict__ qlen)
{
  constexpr int WTM = BM / 2, WTN = BN / 2;
  constexpr int MI = WTM / 16, NI = WTN / 16;

  const int z = blockIdx.z;
  const int tileM = blockIdx.y * BM;
  const int tileN = blockIdx.x * BN;
  if (SKIPQ == 2) { int b = tileM >> 10; if ((tileM & 1023) >= qlen[b]) return; }

  const u16* Bm = (z == 0) ? B0 : (z == 1) ? B1 : B2;
  const float* bias = (z == 0) ? bias0 : (z == 1) ? bias1 : bias2;
  u16* C = (z == 0) ? C0 : (z == 1) ? C1 : C2;
  const bool tr = (z == NPROJ - 1);

  __shared__ __align__(16) u16 smem[(BM + BN) * 32];
  u16* ldsA = smem;
  u16* ldsB = smem + BM * 32;

  const int t = threadIdx.x;
  const int lane = t & 63;
  const int wave = t >> 6;
  const int waveM = wave >> 1;
  const int waveN = wave & 1;
  const int lm = lane & 15;
  const int kg = lane >> 4;

  const u16* Ab = A + (long)tileM * lda;
  const u16* Bb = Bm + (long)tileN * EE;

  f32x4 acc[MI][NI];
#pragma unroll
  for (int i = 0; i < MI; ++i)
#pragma unroll
    for (int j = 0; j < NI; ++j) acc[i][j] = (f32x4){0.f, 0.f, 0.f, 0.f};

  for (int kt = 0; kt < EE; kt += 32) {
    __syncthreads();
#pragma unroll
    for (int i = 0; i < (BM * 4) / 256; ++i) {
      int c = i * 256 + t;
      async16(Ab + (long)(c >> 2) * lda + kt + (c & 3) * 8, ldsA + (c - lane) * 8);
    }
#pragma unroll
    for (int i = 0; i < (BN * 4) / 256; ++i) {
      int c = i * 256 + t;
      async16(Bb + (long)(c >> 2) * EE + kt + (c & 3) * 8, ldsB + (c - lane) * 8);
    }
    __syncthreads();

    s16x8 aF[MI], bF[NI];
#pragma unroll
    for (int i = 0; i < MI; ++i)
      aF[i] = *(const s16x8*)&ldsA[(waveM * WTM + i * 16 + lm) * 32 + kg * 8];
#pragma unroll
    for (int j = 0; j < NI; ++j)
      bF[j] = *(const s16x8*)&ldsB[(waveN * WTN + j * 16 + lm) * 32 + kg * 8];
#pragma unroll
    for (int i = 0; i < MI; ++i)
#pragma unroll
      for (int j = 0; j < NI; ++j)
        acc[i][j] = __builtin_amdgcn_mfma_f32_16x16x32_bf16(aF[i], bF[j], acc[i][j], 0, 0, 0);
  }

  if (!tr) {
#pragma unroll
    for (int j = 0; j < NI; ++j) {
      int n = tileN + waveN * WTN + j * 16 + lm;
      float bv = bias[n];
#pragma unroll
      for (int i = 0; i < MI; ++i)
#pragma unroll
        for (int r = 0; r < 4; ++r) {
          int m = tileM + waveM * WTM + i * 16 + kg * 4 + r;
          int b = m / Lsub, l = m - b * Lsub;
          int h = n >> 6, d = n & 63;
          C[(((long)(b * HH + h) * Lsub + l) << 6) + d] = f2bf(acc[i][j][r] + bv);
        }
    }
  } else {
    constexpr int PAD = BM + 8;
    const int bb = tileM / Lsub;
    const int l0 = tileM - bb * Lsub;
#pragma unroll
    for (int c = 0; c < BN / 32; ++c) {
      __syncthreads();
#pragma unroll
      for (int j = 0; j < NI; ++j) {
        int nloc = waveN * WTN + j * 16 + lm;
        if (nloc >= c * 32 && nloc < c * 32 + 32) {
          int nl = nloc - c * 32;
          float bv = bias[tileN + nloc];
#pragma unroll
          for (int i = 0; i < MI; ++i)
#pragma unroll
            for (int r = 0; r < 4; ++r) {
              int mm = waveM * WTM + i * 16 + kg * 4 + r;
              smem[nl * PAD + mm] = f2bf(acc[i][j][r] + bv);
            }
        }
      }
      __syncthreads();
#pragma unroll
      for (int v = 0; v < (32 * BM) / (256 * 8); ++v) {
        int idx = v * 256 + t;
        int nl = idx / (BM / 8), m8 = idx % (BM / 8);
        int n = tileN + c * 32 + nl;
        int h = n >> 6, d = n & 63;
        *(uint4*)&C[((long)(bb * HH + h) * HD + d) * Lsub + l0 + m8 * 8] =
            *(const uint4*)&smem[nl * PAD + m8 * 8];
      }
    }
  }
}

// cross flash attention: chunk of 512 keys per block (4 tiles, online softmax),
// bf16 partials. SWAPPED QK^T: s = mfma(K,Q) puts q in lane&15, so the k-reduce
// is 31 in-register ops + 2 shfl, mr/lr are scalars, and P writes are b64.
// 1-D grid 2048, XCD-swizzled; K/V prefetch double-buffer in NAMED registers.
// (R6 best config: separate Pl, launch_bounds (256,3). R7-R9 variants regressed.)
__global__ __launch_bounds__(256, 3)
void cross_flash_chunk(const u16* __restrict__ Qc, const u16* __restrict__ Kc,
                       const u16* __restrict__ Vt, u16* __restrict__ Opart,
                       float2* __restrict__ ml, const int* __restrict__ qlen)
{
  const int lin = blockIdx.x;
  const int lid = (lin & 7) * 256 + (lin >> 3);   // bijective: 2048 % 8 == 0
  const int qt = lid & 15;              // 16 q-tiles of 64
  const int bh = (lid >> 4) & 31;       // 32
  const int ck = lid >> 9;              // 4 chunks of 512 keys
  const int b = bh >> 3;
  if (qt * 64 >= qlen[b]) return;

  __shared__ __align__(16) u16 Kt[128 * 72];
  __shared__ __align__(16) u16 Vl[64 * 136];
  __shared__ __align__(16) u16 Pl[4 * 16 * 136];

  const int t = threadIdx.x, lane = t & 63, w = t >> 6;
  const int col = lane & 15, quad = lane >> 4;

  const u16* Qb = Qc + (long)bh * SLQ * HD;
  const u16* Kb = Kc + (long)bh * SLK * HD;
  const u16* Vb = Vt + (long)bh * HD * SLK;

  s16x8 aQ[2];
#pragma unroll
  for (int kk = 0; kk < 2; ++kk)
    aQ[kk] = *(const s16x8*)(Qb + (long)(qt * 64 + w * 16 + col) * HD + kk * 32 + quad * 8);

  f32x4 O[4];
#pragma unroll
  for (int n = 0; n < 4; ++n) O[n] = (f32x4){0.f, 0.f, 0.f, 0.f};
  float mr = -1e30f, lr = 0.f;         // per-lane softmax state for q = col

  u16* Pw = Pl + w * 16 * 136;

  const int krow = t >> 3, kcol = (t & 7) * 8;   // K stage: 128 rows x 64 cols
  const int vrow = t >> 4, vcol = (t & 15) * 8;  // V stage: 64 rows x 128 cols

  // prologue: prefetch tile 0 K/V into NAMED registers (no arrays -> no scratch)
  uint4 kr0, kr1, kr2, kr3, vr0, vr1, vr2, vr3;
  {
    const int kb = ck * 512;
    kr0 = *(const uint4*)(Kb + (long)(kb + krow) * HD + kcol);
    kr1 = *(const uint4*)(Kb + (long)(kb + krow + 32) * HD + kcol);
    kr2 = *(const uint4*)(Kb + (long)(kb + krow + 64) * HD + kcol);
    kr3 = *(const uint4*)(Kb + (long)(kb + krow + 96) * HD + kcol);
    vr0 = *(const uint4*)(Vb + (long)(vrow) * SLK + kb + vcol);
    vr1 = *(const uint4*)(Vb + (long)(vrow + 16) * SLK + kb + vcol);
    vr2 = *(const uint4*)(Vb + (long)(vrow + 32) * SLK + kb + vcol);
    vr3 = *(const uint4*)(Vb + (long)(vrow + 48) * SLK + kb + vcol);
  }

#pragma unroll
  for (int kt = 0; kt < 4; ++kt) {
    __syncthreads();                    // prev tile's LDS reads done
    *(uint4*)&Kt[(krow) * 72 + kcol] = kr0;
    *(uint4*)&Kt[(krow + 32) * 72 + kcol] = kr1;
    *(uint4*)&Kt[(krow + 64) * 72 + kcol] = kr2;
    *(uint4*)&Kt[(krow + 96) * 72 + kcol] = kr3;
    *(uint4*)&Vl[(vrow) * 136 + vcol] = vr0;
    *(uint4*)&Vl[(vrow + 16) * 136 + vcol] = vr1;
    *(uint4*)&Vl[(vrow + 32) * 136 + vcol] = vr2;
    *(uint4*)&Vl[(vrow + 48) * 136 + vcol] = vr3;
    if (kt < 3) {                       // issue next tile's loads; land during compute
      const int kb = ck * 512 + (kt + 1) * 128;
      kr0 = *(const uint4*)(Kb + (long)(kb + krow) * HD + kcol);
      kr1 = *(const uint4*)(Kb + (long)(kb + krow + 32) * HD + kcol);
      kr2 = *(const uint4*)(Kb + (long)(kb + krow + 64) * HD + kcol);
      kr3 = *(const uint4*)(Kb + (long)(kb + krow + 96) * HD + kcol);
      vr0 = *(const uint4*)(Vb + (long)(vrow) * SLK + kb + vcol);
      vr1 = *(const uint4*)(Vb + (long)(vrow + 16) * SLK + kb + vcol);
      vr2 = *(const uint4*)(Vb + (long)(vrow + 32) * SLK + kb + vcol);
      vr3 = *(const uint4*)(Vb + (long)(vrow + 48) * SLK + kb + vcol);
    }
    __syncthreads();                    // tile visible

    // s[j][r] = S[k = j*16 + quad*4 + r][q = col]   (swapped operands)
    f32x4 s[8];
#pragma unroll
    for (int j = 0; j < 8; ++j) s[j] = (f32x4){0.f, 0.f, 0.f, 0.f};
#pragma unroll
    for (int j = 0; j < 8; ++j)
#pragma unroll
      for (int kk = 0; kk < 2; ++kk) {
        s16x8 bK = *(const s16x8*)&Kt[(j * 16 + col) * 72 + kk * 32 + quad * 8];
        s[j] = __builtin_amdgcn_mfma_f32_16x16x32_bf16(bK, aQ[kk], s[j], 0, 0, 0);
      }
#pragma unroll
    for (int j = 0; j < 8; ++j)
#pragma unroll
      for (int r = 0; r < 4; ++r)
        s[j][r] *= 0.125f;

    float tm = s[0][0];
#pragma unroll
    for (int j = 0; j < 8; ++j)
#pragma unroll
      for (int r = 0; r < 4; ++r)
        tm = fmaxf(tm, s[j][r]);
    tm = fmaxf(tm, __shfl_xor(tm, 16));
    tm = fmaxf(tm, __shfl_xor(tm, 32));
    float mnew = fmaxf(mr, tm);
    float alpha = __expf(mr - mnew);
    mr = mnew;
    float ps = 0.f;
#pragma unroll
    for (int j = 0; j < 8; ++j) {
      float p0 = __expf(s[j][0] - mnew);
      float p1 = __expf(s[j][1] - mnew);
      float p2 = __expf(s[j][2] - mnew);
      float p3 = __expf(s[j][3] - mnew);
      ps += (p0 + p1) + (p2 + p3);
      unsigned int lo = (unsigned int)f2bf(p0) | ((unsigned int)f2bf(p1) << 16);
      unsigned int hi = (unsigned int)f2bf(p2) | ((unsigned int)f2bf(p3) << 16);
      *(uint2*)&Pw[col * 136 + j * 16 + quad * 4] = (uint2){lo, hi};
    }
    ps += __shfl_xor(ps, 16);
    ps += __shfl_xor(ps, 32);
    lr = lr * alpha + ps;

    // broadcast alpha to O's q-rows (rows = quad*4+r, alpha lives at lane q)
    float a0 = __shfl(alpha, quad * 4 + 0);
    float a1 = __shfl(alpha, quad * 4 + 1);
    float a2 = __shfl(alpha, quad * 4 + 2);
    float a3 = __shfl(alpha, quad * 4 + 3);
#pragma unroll
    for (int n = 0; n < 4; ++n) {
      O[n][0] *= a0; O[n][1] *= a1; O[n][2] *= a2; O[n][3] *= a3;
    }
#pragma unroll
    for (int kk = 0; kk < 4; ++kk) {
      s16x8 aP = *(const s16x8*)&Pw[col * 136 + kk * 32 + quad * 8];
#pragma unroll
      for (int n = 0; n < 4; ++n) {
        s16x8 bV = *(const s16x8*)&Vl[(n * 16 + col) * 136 + kk * 32 + quad * 8];
        O[n] = __builtin_amdgcn_mfma_f32_16x16x32_bf16(aP, bV, O[n], 0, 0, 0);
      }
    }
  }

#pragma unroll
  for (int r = 0; r < 4; ++r) {
    int q = qt * 64 + w * 16 + quad * 4 + r;
    long gq = (long)bh * SLQ + q;
#pragma unroll
    for (int n = 0; n < 4; ++n)
      Opart[(gq * 4 + ck) * 64 + n * 16 + col] = f2bf(O[n][r]);
  }
  if (quad == 0) {
    int q = qt * 64 + w * 16 + col;
    ml[((long)bh * SLQ + q) * 4 + ck] = (float2){mr, lr};
  }
}

// merge 4 cross chunks -> attn; also emit global (M, L) stats for the weights pass
__global__ __launch_bounds__(256)
void cross_combine(const u16* __restrict__ Opart, const float2* __restrict__ ml,
                   u16* __restrict__ attn, float2* __restrict__ stat,
                   const int* __restrict__ qlen)
{
  int gr = blockIdx.x * 16 + (threadIdx.x >> 4);
  int bh = gr >> 10, q = gr & 1023;
  int b = bh >> 3, h = bh & 7;
  if (q >= qlen[b]) return;
  int d = (threadIdx.x & 15) * 4;
  long base = (long)gr * 4;
  float M = -1e30f;
#pragma unroll
  for (int c = 0; c < 4; ++c) M = fmaxf(M, ml[base + c].x);
  float L = 0.f;
  float ax = 0.f, ay = 0.f, az = 0.f, aw = 0.f;
#pragma unroll
  for (int c = 0; c < 4; ++c) {
    float2 st = ml[base + c];
    float wgt = __expf(st.x - M);
    L += st.y * wgt;
    const u16* p = Opart + (base + c) * 64 + d;
    ax += bf2f(p[0]) * wgt; ay += bf2f(p[1]) * wgt;
    az += bf2f(p[2]) * wgt; aw += bf2f(p[3]) * wgt;
  }
  if (d == 0) stat[gr] = (float2){M, L};
  float inv = 1.0f / L;
  unsigned int lo = (unsigned int)f2bf(ax * inv) | ((unsigned int)f2bf(ay * inv) << 16);
  unsigned int hi = (unsigned int)f2bf(az * inv) | ((unsigned int)f2bf(aw * inv) << 16);
  *(uint2*)&attn[((long)b * SLQ + q) * EE + h * HD + d] = (uint2){lo, hi};
}

// head-mean attention weights by QK^T recompute.
// block = (key tile of 128, q tile of 64, b); K staged in LDS per head,
// software-pipelined over heads; wave owns 16 q rows x 128 keys.
__global__ __launch_bounds__(256, 4)
void wmean_recompute(const u16* __restrict__ Qc, const u16* __restrict__ Kc,
                     const float2* __restrict__ stat, float* __restrict__ outw,
                     const int* __restrict__ qlen)
{
  const int kt = blockIdx.x;             // 16 key tiles of 128
  const int qt = blockIdx.y;             // 16 q tiles of 64
  const int b  = blockIdx.z;             // 4
  const int qn = qlen[b];
  const int q0 = qt * 64;
  const int t = threadIdx.x, lane = t & 63, w = t >> 6;
  const int col = lane & 15, quad = lane >> 4;

  float* wr = outw + ((long)b * SLQ + q0) * SLK + kt * 128;

  if (q0 >= qn) {
    float4 z = {0.f, 0.f, 0.f, 0.f};
    for (int i = t; i < 64 * 32; i += 256) {
      int row = i >> 5, c = (i & 31) << 2;
      *(float4*)&wr[(long)row * SLK + c] = z;
    }
    return;
  }

  __shared__ __align__(16) u16 Kl[128 * 72];

  const int qw = q0 + w * 16;            // wave's 16 q rows
  const u16* Kbase = Kc + ((long)b * HH * SLK + (long)kt * 128) * HD;

  const int krow = t >> 3, kcol = (t & 7) * 8;

  // preload head 0's K tile into NAMED registers
  uint4 kr0, kr1, kr2, kr3;
  kr0 = *(const uint4*)(Kbase + (long)(krow) * HD + kcol);
  kr1 = *(const uint4*)(Kbase + (long)(krow + 32) * HD + kcol);
  kr2 = *(const uint4*)(Kbase + (long)(krow + 64) * HD + kcol);
  kr3 = *(const uint4*)(Kbase + (long)(krow + 96) * HD + kcol);

  f32x4 acc[8];
#pragma unroll
  for (int j = 0; j < 8; ++j) acc[j] = (f32x4){0.f, 0.f, 0.f, 0.f};

#pragma unroll 1
  for (int h = 0; h < 8; ++h) {
    const int bh = b * 8 + h;
    __syncthreads();                     // previous iteration's LDS reads done
    *(uint4*)&Kl[(krow) * 72 + kcol] = kr0;
    *(uint4*)&Kl[(krow + 32) * 72 + kcol] = kr1;
    *(uint4*)&Kl[(krow + 64) * 72 + kcol] = kr2;
    *(uint4*)&Kl[(krow + 96) * 72 + kcol] = kr3;
    if (h < 7) {
      const u16* Kn = Kbase + (long)(h + 1) * SLK * HD;
      kr0 = *(const uint4*)(Kn + (long)(krow) * HD + kcol);
      kr1 = *(const uint4*)(Kn + (long)(krow + 32) * HD + kcol);
      kr2 = *(const uint4*)(Kn + (long)(krow + 64) * HD + kcol);
      kr3 = *(const uint4*)(Kn + (long)(krow + 96) * HD + kcol);
    }
    const u16* Qb = Qc + ((long)bh * SLQ + qw) * HD;
    s16x8 aQ0 = *(const s16x8*)(Qb + col * HD + quad * 8);
    s16x8 aQ1 = *(const s16x8*)(Qb + col * HD + 32 + quad * 8);
    float m_[4], il_[4];
#pragma unroll
    for (int r = 0; r < 4; ++r) {
      float2 st = stat[(long)bh * SLQ + qw + quad * 4 + r];
      m_[r] = st.x; il_[r] = 0.125f / st.y;
    }
    __syncthreads();                     // K tile visible

    f32x4 s[8];
#pragma unroll
    for (int j = 0; j < 8; ++j) s[j] = (f32x4){0.f, 0.f, 0.f, 0.f};
#pragma unroll
    for (int j = 0; j < 8; ++j) {
      s16x8 bK0 = *(const s16x8*)&Kl[(j * 16 + col) * 72 + quad * 8];
      s16x8 bK1 = *(const s16x8*)&Kl[(j * 16 + col) * 72 + 32 + quad * 8];
      s[j] = __builtin_amdgcn_mfma_f32_16x16x32_bf16(aQ0, bK0, s[j], 0, 0, 0);
      s[j] = __builtin_amdgcn_mfma_f32_16x16x32_bf16(aQ1, bK1, s[j], 0, 0, 0);
    }
#pragma unroll
    for (int j = 0; j < 8; ++j)
#pragma unroll
      for (int r = 0; r < 4; ++r)
        acc[j][r] += __expf(s[j][r] * 0.125f - m_[r]) * il_[r];
  }

#pragma unroll
  for (int r = 0; r < 4; ++r) {
    int row = w * 16 + quad * 4 + r;
    bool v = (q0 + row) < qn;
#pragma unroll
    for (int j = 0; j < 8; ++j)
      wr[(long)row * SLK + j * 16 + col] = v ? acc[j][r] : 0.f;
  }
}

// self-attention: chunk of 256 keys per block (2 tiles, online softmax), bf16 partials.
// SWAPPED QK^T (R6 best config). 1-D grid, XCD-swizzled; named-reg prefetch.
__global__ __launch_bounds__(256, 3)
void self_flash_chunk(const u16* __restrict__ Qc, const u16* __restrict__ Kc,
                      const u16* __restrict__ Vt, u16* __restrict__ Opart,
                      float2* __restrict__ ml, const int* __restrict__ qlen)
{
  const int lin = blockIdx.x;
  const int lid = (lin & 7) * 256 + (lin >> 3);   // bijective: 2048 % 8 == 0
  const int qt = lid & 15;
  const int bh = (lid >> 4) & 31;
  const int ck = lid >> 9;               // 4 chunks of 256
  const int b = bh >> 3;
  const int kmax = qlen[b];
  if (qt * 64 >= kmax || ck * 256 >= kmax) return;

  __shared__ __align__(16) u16 Kt[128 * 72];
  __shared__ __align__(16) u16 Vl[64 * 136];
  __shared__ __align__(16) u16 Pl[4 * 16 * 136];

  const int t = threadIdx.x, lane = t & 63, w = t >> 6;
  const int col = lane & 15, quad = lane >> 4;

  const u16* Qb = Qc + (long)bh * SLQ * HD;
  const u16* Kb = Kc + (long)bh * SLQ * HD;
  const u16* Vb = Vt + (long)bh * HD * SLQ;

  s16x8 aQ[2];
#pragma unroll
  for (int kk = 0; kk < 2; ++kk)
    aQ[kk] = *(const s16x8*)(Qb + (long)(qt * 64 + w * 16 + col) * HD + kk * 32 + quad * 8);

  f32x4 O[4];
#pragma unroll
  for (int n = 0; n < 4; ++n) O[n] = (f32x4){0.f, 0.f, 0.f, 0.f};
  float mr = -1e30f, lr = 0.f;

  u16* Pw = Pl + w * 16 * 136;

  const int krow = t >> 3, kcol = (t & 7) * 8;
  const int vrow = t >> 4, vcol = (t & 15) * 8;

  // prologue: prefetch tile 0 (always within buffer; max addr < SLQ)
  uint4 kr0, kr1, kr2, kr3, vr0, vr1, vr2, vr3;
  {
    const int kb = ck * 256;
    kr0 = *(const uint4*)(Kb + (long)(kb + krow) * HD + kcol);
    kr1 = *(const uint4*)(Kb + (long)(kb + krow + 32) * HD + kcol);
    kr2 = *(const uint4*)(Kb + (long)(kb + krow + 64) * HD + kcol);
    kr3 = *(const uint4*)(Kb + (long)(kb + krow + 96) * HD + kcol);
    vr0 = *(const uint4*)(Vb + (long)(vrow) * SLQ + kb + vcol);
    vr1 = *(const uint4*)(Vb + (long)(vrow + 16) * SLQ + kb + vcol);
    vr2 = *(const uint4*)(Vb + (long)(vrow + 32) * SLQ + kb + vcol);
    vr3 = *(const uint4*)(Vb + (long)(vrow + 48) * SLQ + kb + vcol);
  }

#pragma unroll
  for (int kt = 0; kt < 2; ++kt) {
    const int k0 = ck * 256 + kt * 128;
    if (k0 >= kmax) break;               // block-uniform
    __syncthreads();
    *(uint4*)&Kt[(krow) * 72 + kcol] = kr0;
    *(uint4*)&Kt[(krow + 32) * 72 + kcol] = kr1;
    *(uint4*)&Kt[(krow + 64) * 72 + kcol] = kr2;
    *(uint4*)&Kt[(krow + 96) * 72 + kcol] = kr3;
    *(uint4*)&Vl[(vrow) * 136 + vcol] = vr0;
    *(uint4*)&Vl[(vrow + 16) * 136 + vcol] = vr1;
    *(uint4*)&Vl[(vrow + 32) * 136 + vcol] = vr2;
    *(uint4*)&Vl[(vrow + 48) * 136 + vcol] = vr3;
    if (kt < 1) {
      const int kb = ck * 256 + 128;     // in-bounds (max 896+127 < 1024)
      kr0 = *(const uint4*)(Kb + (long)(kb + krow) * HD + kcol);
      kr1 = *(const uint4*)(Kb + (long)(kb + krow + 32) * HD + kcol);
      kr2 = *(const uint4*)(Kb + (long)(kb + krow + 64) * HD + kcol);
      kr3 = *(const uint4*)(Kb + (long)(kb + krow + 96) * HD + kcol);
      vr0 = *(const uint4*)(Vb + (long)(vrow) * SLQ + kb + vcol);
      vr1 = *(const uint4*)(Vb + (long)(vrow + 16) * SLQ + kb + vcol);
      vr2 = *(const uint4*)(Vb + (long)(vrow + 32) * SLQ + kb + vcol);
      vr3 = *(const uint4*)(Vb + (long)(vrow + 48) * SLQ + kb + vcol);
    }
    __syncthreads();

    // s[j][r] = S[k = k0 + j*16 + quad*4 + r][q = col]
    f32x4 s[8];
#pragma unroll
    for (int j = 0; j < 8; ++j) s[j] = (f32x4){0.f, 0.f, 0.f, 0.f};
#pragma unroll
    for (int j = 0; j < 8; ++j)
#pragma unroll
      for (int kk = 0; kk < 2; ++kk) {
        s16x8 bK = *(const s16x8*)&Kt[(j * 16 + col) * 72 + kk * 32 + quad * 8];
        s[j] = __builtin_amdgcn_mfma_f32_16x16x32_bf16(bK, aQ[kk], s[j], 0, 0, 0);
      }
#pragma unroll
    for (int j = 0; j < 8; ++j)
#pragma unroll
      for (int r = 0; r < 4; ++r) {
        bool ok = (k0 + j * 16 + quad * 4 + r) < kmax;
        s[j][r] = ok ? s[j][r] * 0.125f : -1e30f;
      }

    float tm = s[0][0];
#pragma unroll
    for (int j = 0; j < 8; ++j)
#pragma unroll
      for (int r = 0; r < 4; ++r)
        tm = fmaxf(tm, s[j][r]);
    tm = fmaxf(tm, __shfl_xor(tm, 16));
    tm = fmaxf(tm, __shfl_xor(tm, 32));
    float mnew = fmaxf(mr, tm);
    float alpha = __expf(mr - mnew);
    mr = mnew;
    float ps = 0.f;
#pragma unroll
    for (int j = 0; j < 8; ++j) {
      float p0 = __expf(s[j][0] - mnew);
      float p1 = __expf(s[j][1] - mnew);
      float p2 = __expf(s[j][2] - mnew);
      float p3 = __expf(s[j][3] - mnew);
      ps += (p0 + p1) + (p2 + p3);
      unsigned int lo = (unsigned int)f2bf(p0) | ((unsigned int)f2bf(p1) << 16);
      unsigned int hi = (unsigned int)f2bf(p2) | ((unsigned int)f2bf(p3) << 16);
      *(uint2*)&Pw[col * 136 + j * 16 + quad * 4] = (uint2){lo, hi};
    }
    ps += __shfl_xor(ps, 16);
    ps += __shfl_xor(ps, 32);
    lr = lr * alpha + ps;

    float a0 = __shfl(alpha, quad * 4 + 0);
    float a1 = __shfl(alpha, quad * 4 + 1);
    float a2 = __shfl(alpha, quad * 4 + 2);
    float a3 = __shfl(alpha, quad * 4 + 3);
#pragma unroll
    for (int n = 0; n < 4; ++n) {
      O[n][0] *= a0; O[n][1] *= a1; O[n][2] *= a2; O[n][3] *= a3;
    }
#pragma unroll
    for (int kk = 0; kk < 4; ++kk) {
      s16x8 aP = *(const s16x8*)&Pw[col * 136 + kk * 32 + quad * 8];
#pragma unroll
      for (int n = 0; n < 4; ++n) {
        s16x8 bV = *(const s16x8*)&Vl[(n * 16 + col) * 136 + kk * 32 + quad * 8];
        O[n] = __builtin_amdgcn_mfma_f32_16x16x32_bf16(aP, bV, O[n], 0, 0, 0);
      }
    }
  }

#pragma unroll
  for (int r = 0; r < 4; ++r) {
    int q = qt * 64 + w * 16 + quad * 4 + r;
    long gq = (long)bh * SLQ + q;
#pragma unroll
    for (int n = 0; n < 4; ++n)
      Opart[(gq * 4 + ck) * 64 + n * 16 + col] = f2bf(O[n][r]);
  }
  if (quad == 0) {
    int q = qt * 64 + w * 16 + col;
    ml[((long)bh * SLQ + q) * 4 + ck] = (float2){mr, lr};
  }
}

__global__ __launch_bounds__(256)
void self_combine(const u16* __restrict__ Opart, const float2* __restrict__ ml,
                  u16* __restrict__ attn, const int* __restrict__ qlen)
{
  int gr = blockIdx.x * 16 + (threadIdx.x >> 4);
  int bh = gr >> 10, q = gr & 1023;
  int b = bh >> 3, h = bh & 7;
  int kmax = qlen[b];
  if (q >= kmax) return;
  int NC = (kmax + 255) >> 8;
  int d = (threadIdx.x & 15) * 4;
  long base = (long)gr * 4;
  float M = -1e30f;
  for (int c = 0; c < NC; ++c) M = fmaxf(M, ml[base + c].x);
  float L = 0.f;
  float ax = 0.f, ay = 0.f, az = 0.f, aw = 0.f;
  for (int c = 0; c < NC; ++c) {
    float2 st = ml[base + c];
    float wgt = __expf(st.x - M);
    L += st.y * wgt;
    const u16* p = Opart + (base + c) * 64 + d;
    ax += bf2f(p[0]) * wgt; ay += bf2f(p[1]) * wgt;
    az += bf2f(p[2]) * wgt; aw += bf2f(p[3]) * wgt;
  }
  float inv = 1.0f / L;
  unsigned int lo = (unsigned int)f2bf(ax * inv) | ((unsigned int)f2bf(ay * inv) << 16);
  unsigned int hi = (unsigned int)f2bf(az * inv) | ((unsigned int)f2bf(aw * inv) << 16);
  *(uint2*)&attn[((long)b * SLQ + q) * EE + h * HD + d] = (uint2){lo, hi};
}

// fused input conversion: masked queries + keys + 9 weight matrices
__global__ __launch_bounds__(256)
void cvt_all(const float* __restrict__ queries, const float* __restrict__ keys,
             const int* __restrict__ qlen,
             const float* w0, const float* w1, const float* w2, const float* w3,
             const float* w4, const float* w5, const float* w6, const float* w7,
             const float* w8,
             u16* __restrict__ q0, u16* __restrict__ keysb, u16* __restrict__ Wb) {
  int blk = blockIdx.x;
  int t = threadIdx.x;
  const float* src;
  u16* dst;
  long off;
  bool mask = false;
  int b = 0, q = 0;
  if (blk < 1024) {
    off = (long)blk * 2048 + t * 8;
    int row = (int)(off >> 9);
    b = row >> 10; q = row & 1023;
    mask = true;
    src = queries; dst = q0;
  } else if (blk < 3072) {
    off = (long)(blk - 1024) * 2048 + t * 8;
    src = keys; dst = keysb;
  } else {
    int mat = (blk - 3072) >> 7, part = (blk - 3072) & 127;
    const float* srcs[9] = {w0, w1, w2, w3, w4, w5, w6, w7, w8};
    src = srcs[mat];
    off = (long)part * 2048 + t * 8;
    dst = Wb + (long)mat * EE * EE;
  }
  s16x8 o = (s16x8){0, 0, 0, 0, 0, 0, 0, 0};
  if (!mask || q < qlen[b]) {
    float4 a = *(const float4*)&src[off];
    float4 c = *(const float4*)&src[off + 4];
    o[0] = (short)f2bf(a.x); o[1] = (short)f2bf(a.y);
    o[2] = (short)f2bf(a.z); o[3] = (short)f2bf(a.w);
    o[4] = (short)f2bf(c.x); o[5] = (short)f2bf(c.y);
    o[6] = (short)f2bf(c.z); o[7] = (short)f2bf(c.w);
  }
  *(s16x8*)&dst[off] = o;
}

__device__ __forceinline__ float blockSum(float v, float* red4) {
#pragma unroll
  for (int o = 32; o; o >>= 1) v += __shfl_xor(v, o);
  if ((threadIdx.x & 63) == 0) red4[threadIdx.x >> 6] = v;
  __syncthreads();
  v = red4[0] + red4[1] + red4[2] + red4[3];
  __syncthreads();
  return v;
}

template<int OUTF32>
__global__ __launch_bounds__(256)
void silu_ln_kernel(const u16* __restrict__ x1, const u16* __restrict__ x2,
                    const float* __restrict__ g, const float* __restrict__ beta,
                    const int* __restrict__ qlen, void* __restrict__ outv, int mode) {
  int row = blockIdx.x;
  int b = row >> 10, q = row & 1023;
  int t = threadIdx.x;
  if (mode && q >= qlen[b]) {
    if (mode == 1) {
      if (OUTF32) {
        float* o = (float*)outv + (long)row * EE;
        o[2 * t] = 0.f; o[2 * t + 1] = 0.f;
      } else {
        u16* o = (u16*)outv + (long)row * EE;
        *(unsigned int*)&o[2 * t] = 0u;
      }
    }
    return;
  }
  __shared__ float red4[4];
  const u16* p1 = x1 + (long)row * EE;
  const u16* p2 = x2 + (long)row * EE;
  float a0 = bf2f(p1[2 * t]) + bf2f(p2[2 * t]);
  float a1 = bf2f(p1[2 * t + 1]) + bf2f(p2[2 * t + 1]);
  a0 = a0 / (1.f + __expf(-a0));
  a1 = a1 / (1.f + __expf(-a1));
  float mu = blockSum(a0 + a1, red4) * (1.f / 512.f);
  float d0 = a0 - mu, d1 = a1 - mu;
  float var = blockSum(d0 * d0 + d1 * d1, red4) * (1.f / 512.f);
  float rs = rsqrtf(var + 1e-5f);
  float r0 = d0 * rs * g[2 * t] + beta[2 * t];
  float r1 = d1 * rs * g[2 * t + 1] + beta[2 * t + 1];
  if (OUTF32) {
    float* o = (float*)outv + (long)row * EE;
    o[2 * t] = r0; o[2 * t + 1] = r1;
  } else {
    u16* o = (u16*)outv + (long)row * EE;
    o[2 * t] = f2bf(r0); o[2 * t + 1] = f2bf(r1);
  }
}

extern "C" void kernel_launch(void* const* d_in, const int* in_sizes, int n_in,
                              void* d_out, int out_size, void* d_ws, size_t ws_size,
                              hipStream_t stream) {
  const float* queries = (const float*)d_in[0];
  const float* keys    = (const float*)d_in[1];
  const int*   qlen    = (const int*)d_in[2];
  const float* cWq = (const float*)d_in[3],  *cbq = (const float*)d_in[4];
  const float* cWk = (const float*)d_in[5],  *cbk = (const float*)d_in[6];
  const float* cWv = (const float*)d_in[7],  *cbv = (const float*)d_in[8];
  const float* cWo = (const float*)d_in[9],  *cbo = (const float*)d_in[10];
  const float* sWq = (const float*)d_in[11], *sbq = (const float*)d_in[12];
  const float* sWk = (const float*)d_in[13], *sbk = (const float*)d_in[14];
  const float* sWv = (const float*)d_in[15], *sbv = (const float*)d_in[16];
  const float* sWo = (const float*)d_in[17], *sbo = (const float*)d_in[18];
  const float* Wf  = (const float*)d_in[19], *bfb = (const float*)d_in[20];
  const float* g_cross = (const float*)d_in[21], *b_cross = (const float*)d_in[22];
  const float* g_ffn   = (const float*)d_in[23], *b_ffn   = (const float*)d_in[24];
  const float* g_self  = (const float*)d_in[25], *b_self  = (const float*)d_in[26];

  float* out_q = (float*)d_out;
  float* out_w = out_q + (long)BB * SLQ * EE;

  u16* ws = (u16*)d_ws;
  u16* S     = ws;                               // region kept for layout; cross S no longer materialized
  u16* Qc    = S   + (long)BB * HH * SLQ * SLK;
  u16* Kc    = Qc  + (long)BB * HH * SLQ * HD;
  u16* Vt    = Kc  + (long)BB * HH * SLK * HD;
  u16* q0    = Vt  + (long)BB * HH * SLK * HD;
  u16* keysb = q0  + (long)BB * SLQ * EE;
  u16* attn  = keysb + (long)BB * SLK * EE;
  u16* proj  = attn + (long)BB * SLQ * EE;
  u16* q1    = proj + (long)BB * SLQ * EE;
  u16* fbuf  = q1  + (long)BB * SLQ * EE;
  u16* q2    = fbuf + (long)BB * SLQ * EE;
  u16* Wb    = q2  + (long)BB * SLQ * EE;
  const long WSLOT = (long)EE * EE;
  u16*    Cpb  = Wb + 9 * WSLOT;                  // cross O partials bf16: 32768*4*64
  float2* stat = (float2*)(Cpb + 8388608);        // 32768 float2 (M, L)

  // cross flash ml lives in the (now dead) S region, clear of the self overlay below
  float2* mlC = (float2*)(S + 33554432);          // 32768*4 float2

  // self partials overlay S (front of region)
  u16*    OpS = S;                                // 32768*4*64 bf16
  float2* mlS = (float2*)(S + 8388608);           // 32768*4 float2

  u16* bWq = Wb + 0 * WSLOT; u16* bWk = Wb + 1 * WSLOT; u16* bWv = Wb + 2 * WSLOT;
  u16* bWo = Wb + 3 * WSLOT; u16* bsWq = Wb + 4 * WSLOT; u16* bsWk = Wb + 5 * WSLOT;
  u16* bsWv = Wb + 6 * WSLOT; u16* bsWo = Wb + 7 * WSLOT; u16* bWf = Wb + 8 * WSLOT;

  dim3 blk(256);
  const int MQ = BB * SLQ;   // 4096
  const int MK = BB * SLK;   // 8192

  cvt_all<<<dim3(3072 + 9 * 128), blk, 0, stream>>>(
      queries, keys, qlen, cWq, cWk, cWv, cWo, sWq, sWk, sWv, sWo, Wf, q0, keysb, Wb);

  // cross Q projection
  gemm_nt<64, 64, 1, 2><<<dim3(EE / 64, MQ / 64, 1), blk, 0, stream>>>(
      q0, bWq, cbq, Qc, MQ, EE, EE, EE, EE, 0, 0, 0, 0, 1.0f, SLQ, qlen);
  // cross K+V projections in one dispatch
  gemm_proj<64, 64, 0, 2><<<dim3(EE / 64, MK / 64, 2), blk, 0, stream>>>(
      keysb, bWk, bWv, nullptr, cbk, cbv, nullptr, Kc, Vt, nullptr, MK, EE, SLK, qlen);

  // fused cross attention: no S materialization (1-D swizzled grid)
  cross_flash_chunk<<<dim3(2048), blk, 0, stream>>>(Qc, Kc, Vt, Cpb, mlC, qlen);
  cross_combine<<<dim3(2048), blk, 0, stream>>>(Cpb, mlC, attn, stat, qlen);
  // head-mean attention weights via QK^T recompute (LDS-staged, head-pipelined)
  wmean_recompute<<<dim3(16, 16, BB), blk, 0, stream>>>(Qc, Kc, stat, out_w, qlen);

  gemm_nt<128, 128, 0, 2><<<dim3(EE / 128, MQ / 128, 1), blk, 0, stream>>>(
      attn, bWo, cbo, proj, MQ, EE, EE, EE, EE, EE, 0, 0, 0, 1.0f, SLQ, qlen);

  silu_ln_kernel<0><<<dim3(MQ), blk, 0, stream>>>(proj, q0, g_cross, b_cross, qlen, q1, 2);

  gemm_nt<128, 128, 0, 2><<<dim3(EE / 128, MQ / 128, 1), blk, 0, stream>>>(
      q1, bWf, bfb, fbuf, MQ, EE, EE, EE, EE, EE, 0, 0, 0, 1.0f, SLQ, qlen);

  silu_ln_kernel<0><<<dim3(MQ), blk, 0, stream>>>(q1, fbuf, g_ffn, b_ffn, qlen, q2, 1);

  // self Q/K/V projections in one dispatch
  gemm_proj<64, 64, 2, 3><<<dim3(EE / 64, MQ / 64, 3), blk, 0, stream>>>(
      q2, bsWq, bsWk, bsWv, sbq, sbk, sbv, Qc, Kc, Vt, MQ, EE, SLQ, qlen);

  // fused self attention (partials overlay S; 1-D swizzled grid)
  self_flash_chunk<<<dim3(2048), blk, 0, stream>>>(Qc, Kc, Vt, OpS, mlS, qlen);
  self_combine<<<dim3(2048), blk, 0, stream>>>(OpS, mlS, attn, qlen);

  gemm_nt<128, 128, 0, 2><<<dim3(EE / 128, MQ / 128, 1), blk, 0, stream>>>(
      attn, bsWo, sbo, proj, MQ, EE, EE, EE, EE, EE, 0, 0, 0, 1.0f, SLQ, qlen);

  silu_ln_kernel<1><<<dim3(MQ), blk, 0, stream>>>(q2, proj, g_self, b_self, qlen, out_q, 1);
}

// Round 11
// 295.324 us; speedup vs baseline: 1.2434x; 1.0643x over previous
//
#include <hip/hip_runtime.h>

#define BB 4
#define SLQ 1024
#define SLK 2048
#define EE 512
#define HH 8
#define HD 64

typedef unsigned short u16;
typedef __attribute__((ext_vector_type(8))) short s16x8;
typedef __attribute__((ext_vector_type(4))) float f32x4;

__device__ __forceinline__ float bf2f(u16 u) {
  union { unsigned int i; float f; } v; v.i = ((unsigned int)u) << 16; return v.f;
}
__device__ __forceinline__ u16 f2bf(float f) {
  union { float f; unsigned int i; } v; v.f = f;
  unsigned int i = v.i;
  return (u16)((i + 0x7fffu + ((i >> 16) & 1u)) >> 16);
}

__device__ __forceinline__ void async16(const u16* g, u16* l) {
  __builtin_amdgcn_global_load_lds(
      (const __attribute__((address_space(1))) unsigned int*)g,
      (__attribute__((address_space(3))) unsigned int*)l, 16, 0, 0);
}

// NT GEMM: C[m,n] = alpha*sum_k A[m,k]*B[n,k] + bias[n]
// MODE 0: row-major, per-wave barrier-free staged write
// MODE 1: head-split [B,H,Lsub,64] direct scatter
// SKIPQ 0: none; 1: b=z>>3, skip tileM>=qlen[b]; 2: b=tileM>>10 (Lsub=1024)
template<int BM, int BN, int MODE, int SKIPQ>
__global__ __launch_bounds__(256, (BM == 128 ? 4 : 6))
void gemm_nt(const u16* __restrict__ A, const u16* __restrict__ Bm,
             const float* __restrict__ bias, u16* __restrict__ C,
             int M, int N, int K, int lda, int ldb, int ldc,
             long sAz, long sBz, long sCz, float alpha, int Lsub,
             const int* __restrict__ qlen)
{
  constexpr int WTM = BM / 2, WTN = BN / 2;
  constexpr int MI = WTM / 16, NI = WTN / 16;
  constexpr int EPAD = WTN + 8;
  constexpr int SM1 = (BM + BN) * 32;
  constexpr int SM2 = (MODE == 0) ? 4 * WTM * EPAD : 0;
  constexpr int SM = (SM1 > SM2) ? SM1 : SM2;

  const int z = blockIdx.z;
  const int tileM = blockIdx.y * BM;
  const int tileN = blockIdx.x * BN;

  if (SKIPQ == 1) { if (tileM >= qlen[z >> 3]) return; }
  if (SKIPQ == 2) { int b = tileM >> 10; if ((tileM & 1023) >= qlen[b]) return; }

  __shared__ __align__(16) u16 smem[SM];
  u16* ldsA = smem;
  u16* ldsB = smem + BM * 32;

  const int t = threadIdx.x;
  const int lane = t & 63;
  const int wave = t >> 6;
  const int waveM = wave >> 1;
  const int waveN = wave & 1;
  const int lm = lane & 15;
  const int kg = lane >> 4;

  const u16* Ab = A + (long)z * sAz + (long)tileM * lda;
  const u16* Bb = Bm + (long)z * sBz + (long)tileN * ldb;

  f32x4 acc[MI][NI];
#pragma unroll
  for (int i = 0; i < MI; ++i)
#pragma unroll
    for (int j = 0; j < NI; ++j) acc[i][j] = (f32x4){0.f, 0.f, 0.f, 0.f};

  for (int kt = 0; kt < K; kt += 32) {
    __syncthreads();
#pragma unroll
    for (int i = 0; i < (BM * 4) / 256; ++i) {
      int c = i * 256 + t;
      async16(Ab + (long)(c >> 2) * lda + kt + (c & 3) * 8, ldsA + (c - lane) * 8);
    }
#pragma unroll
    for (int i = 0; i < (BN * 4) / 256; ++i) {
      int c = i * 256 + t;
      async16(Bb + (long)(c >> 2) * ldb + kt + (c & 3) * 8, ldsB + (c - lane) * 8);
    }
    __syncthreads();

    s16x8 aF[MI], bF[NI];
#pragma unroll
    for (int i = 0; i < MI; ++i)
      aF[i] = *(const s16x8*)&ldsA[(waveM * WTM + i * 16 + lm) * 32 + kg * 8];
#pragma unroll
    for (int j = 0; j < NI; ++j)
      bF[j] = *(const s16x8*)&ldsB[(waveN * WTN + j * 16 + lm) * 32 + kg * 8];
#pragma unroll
    for (int i = 0; i < MI; ++i)
#pragma unroll
      for (int j = 0; j < NI; ++j)
        acc[i][j] = __builtin_amdgcn_mfma_f32_16x16x32_bf16(aF[i], bF[j], acc[i][j], 0, 0, 0);
  }

  if (MODE == 0) {
    // per-wave staged write: no cross-wave barriers in the store phase
    u16* ep = smem + wave * (WTM * EPAD);
    __syncthreads();
#pragma unroll
    for (int i = 0; i < MI; ++i)
#pragma unroll
      for (int j = 0; j < NI; ++j) {
        int n = waveN * WTN + j * 16 + lm;
        float bv = bias ? bias[tileN + n] : 0.0f;
#pragma unroll
        for (int r = 0; r < 4; ++r)
          ep[(i * 16 + kg * 4 + r) * EPAD + j * 16 + lm] = f2bf(acc[i][j][r] * alpha + bv);
      }
    const long Crow = (long)z * sCz + (long)(tileM + waveM * WTM) * ldc + tileN + waveN * WTN;
#pragma unroll
    for (int it = 0; it < (WTM * WTN) / 512; ++it) {
      int idx = it * 64 + lane;
      int row = idx / (WTN / 8), seg = idx % (WTN / 8);
      *(uint4*)&C[Crow + (long)row * ldc + seg * 8] =
          *(const uint4*)&ep[row * EPAD + seg * 8];
    }
  } else {
#pragma unroll
    for (int j = 0; j < NI; ++j) {
      int n = tileN + waveN * WTN + j * 16 + lm;
      float bv = bias ? bias[n] : 0.0f;
#pragma unroll
      for (int i = 0; i < MI; ++i) {
#pragma unroll
        for (int r = 0; r < 4; ++r) {
          int m = tileM + waveM * WTM + i * 16 + kg * 4 + r;
          float v = acc[i][j][r] * alpha + bv;
          int b = m / Lsub, l = m - b * Lsub;
          int h = n >> 6, d = n & 63;
          C[(((long)(b * HH + h) * Lsub + l) << 6) + d] = f2bf(v);
        }
      }
    }
  }
}

// multi-projection: z selects weight/bias/output; z<NPROJ-1 -> head-split [B,H,L,64],
// z==NPROJ-1 -> transposed [B,H,64,L] staged write. K = EE, N = EE.
template<int BM, int BN, int SKIPQ, int NPROJ>
__global__ __launch_bounds__(256, (BM == 128 ? 4 : 6))
void gemm_proj(const u16* __restrict__ A,
               const u16* B0, const u16* B1, const u16* B2,
               const float* bias0, const float* bias1, const float* bias2,
               u16* C0, u16* C1, u16* C2,
               int M, int lda, int Lsub, const int* __restrict__ qlen)
{
  constexpr int WTM = BM / 2, WTN = BN / 2;
  constexpr int MI = WTM / 16, NI = WTN / 16;

  const int z = blockIdx.z;
  const int tileM = blockIdx.y * BM;
  const int tileN = blockIdx.x * BN;
  if (SKIPQ == 2) { int b = tileM >> 10; if ((tileM & 1023) >= qlen[b]) return; }

  const u16* Bm = (z == 0) ? B0 : (z == 1) ? B1 : B2;
  const float* bias = (z == 0) ? bias0 : (z == 1) ? bias1 : bias2;
  u16* C = (z == 0) ? C0 : (z == 1) ? C1 : C2;
  const bool tr = (z == NPROJ - 1);

  __shared__ __align__(16) u16 smem[(BM + BN) * 32];
  u16* ldsA = smem;
  u16* ldsB = smem + BM * 32;

  const int t = threadIdx.x;
  const int lane = t & 63;
  const int wave = t >> 6;
  const int waveM = wave >> 1;
  const int waveN = wave & 1;
  const int lm = lane & 15;
  const int kg = lane >> 4;

  const u16* Ab = A + (long)tileM * lda;
  const u16* Bb = Bm + (long)tileN * EE;

  f32x4 acc[MI][NI];
#pragma unroll
  for (int i = 0; i < MI; ++i)
#pragma unroll
    for (int j = 0; j < NI; ++j) acc[i][j] = (f32x4){0.f, 0.f, 0.f, 0.f};

  for (int kt = 0; kt < EE; kt += 32) {
    __syncthreads();
#pragma unroll
    for (int i = 0; i < (BM * 4) / 256; ++i) {
      int c = i * 256 + t;
      async16(Ab + (long)(c >> 2) * lda + kt + (c & 3) * 8, ldsA + (c - lane) * 8);
    }
#pragma unroll
    for (int i = 0; i < (BN * 4) / 256; ++i) {
      int c = i * 256 + t;
      async16(Bb + (long)(c >> 2) * EE + kt + (c & 3) * 8, ldsB + (c - lane) * 8);
    }
    __syncthreads();

    s16x8 aF[MI], bF[NI];
#pragma unroll
    for (int i = 0; i < MI; ++i)
      aF[i] = *(const s16x8*)&ldsA[(waveM * WTM + i * 16 + lm) * 32 + kg * 8];
#pragma unroll
    for (int j = 0; j < NI; ++j)
      bF[j] = *(const s16x8*)&ldsB[(waveN * WTN + j * 16 + lm) * 32 + kg * 8];
#pragma unroll
    for (int i = 0; i < MI; ++i)
#pragma unroll
      for (int j = 0; j < NI; ++j)
        acc[i][j] = __builtin_amdgcn_mfma_f32_16x16x32_bf16(aF[i], bF[j], acc[i][j], 0, 0, 0);
  }

  if (!tr) {
#pragma unroll
    for (int j = 0; j < NI; ++j) {
      int n = tileN + waveN * WTN + j * 16 + lm;
      float bv = bias[n];
#pragma unroll
      for (int i = 0; i < MI; ++i)
#pragma unroll
        for (int r = 0; r < 4; ++r) {
          int m = tileM + waveM * WTM + i * 16 + kg * 4 + r;
          int b = m / Lsub, l = m - b * Lsub;
          int h = n >> 6, d = n & 63;
          C[(((long)(b * HH + h) * Lsub + l) << 6) + d] = f2bf(acc[i][j][r] + bv);
        }
    }
  } else {
    constexpr int PAD = BM + 8;
    const int bb = tileM / Lsub;
    const int l0 = tileM - bb * Lsub;
#pragma unroll
    for (int c = 0; c < BN / 32; ++c) {
      __syncthreads();
#pragma unroll
      for (int j = 0; j < NI; ++j) {
        int nloc = waveN * WTN + j * 16 + lm;
        if (nloc >= c * 32 && nloc < c * 32 + 32) {
          int nl = nloc - c * 32;
          float bv = bias[tileN + nloc];
#pragma unroll
          for (int i = 0; i < MI; ++i)
#pragma unroll
            for (int r = 0; r < 4; ++r) {
              int mm = waveM * WTM + i * 16 + kg * 4 + r;
              smem[nl * PAD + mm] = f2bf(acc[i][j][r] + bv);
            }
        }
      }
      __syncthreads();
#pragma unroll
      for (int v = 0; v < (32 * BM) / (256 * 8); ++v) {
        int idx = v * 256 + t;
        int nl = idx / (BM / 8), m8 = idx % (BM / 8);
        int n = tileN + c * 32 + nl;
        int h = n >> 6, d = n & 63;
        *(uint4*)&C[((long)(bb * HH + h) * HD + d) * Lsub + l0 + m8 * 8] =
            *(const uint4*)&smem[nl * PAD + m8 * 8];
      }
    }
  }
}

// cross flash attention: chunk of 512 keys per block (4 tiles, online softmax),
// bf16 partials. SWAPPED QK^T: s = mfma(K,Q) puts q in lane&15, so the k-reduce
// is 31 in-register ops + 2 shfl, mr/lr are scalars, and P writes are b64.
// 1-D grid 2048, XCD-swizzled; K/V prefetch double-buffer in NAMED registers.
// (R6 best config: separate Pl, launch_bounds (256,3). R7-R9 variants regressed.)
__global__ __launch_bounds__(256, 3)
void cross_flash_chunk(const u16* __restrict__ Qc, const u16* __restrict__ Kc,
                       const u16* __restrict__ Vt, u16* __restrict__ Opart,
                       float2* __restrict__ ml, const int* __restrict__ qlen)
{
  const int lin = blockIdx.x;
  const int lid = (lin & 7) * 256 + (lin >> 3);   // bijective: 2048 % 8 == 0
  const int qt = lid & 15;              // 16 q-tiles of 64
  const int bh = (lid >> 4) & 31;       // 32
  const int ck = lid >> 9;              // 4 chunks of 512 keys
  const int b = bh >> 3;
  if (qt * 64 >= qlen[b]) return;

  __shared__ __align__(16) u16 Kt[128 * 72];
  __shared__ __align__(16) u16 Vl[64 * 136];
  __shared__ __align__(16) u16 Pl[4 * 16 * 136];

  const int t = threadIdx.x, lane = t & 63, w = t >> 6;
  const int col = lane & 15, quad = lane >> 4;

  const u16* Qb = Qc + (long)bh * SLQ * HD;
  const u16* Kb = Kc + (long)bh * SLK * HD;
  const u16* Vb = Vt + (long)bh * HD * SLK;

  s16x8 aQ[2];
#pragma unroll
  for (int kk = 0; kk < 2; ++kk)
    aQ[kk] = *(const s16x8*)(Qb + (long)(qt * 64 + w * 16 + col) * HD + kk * 32 + quad * 8);

  f32x4 O[4];
#pragma unroll
  for (int n = 0; n < 4; ++n) O[n] = (f32x4){0.f, 0.f, 0.f, 0.f};
  float mr = -1e30f, lr = 0.f;         // per-lane softmax state for q = col

  u16* Pw = Pl + w * 16 * 136;

  const int krow = t >> 3, kcol = (t & 7) * 8;   // K stage: 128 rows x 64 cols
  const int vrow = t >> 4, vcol = (t & 15) * 8;  // V stage: 64 rows x 128 cols

  // prologue: prefetch tile 0 K/V into NAMED registers (no arrays -> no scratch)
  uint4 kr0, kr1, kr2, kr3, vr0, vr1, vr2, vr3;
  {
    const int kb = ck * 512;
    kr0 = *(const uint4*)(Kb + (long)(kb + krow) * HD + kcol);
    kr1 = *(const uint4*)(Kb + (long)(kb + krow + 32) * HD + kcol);
    kr2 = *(const uint4*)(Kb + (long)(kb + krow + 64) * HD + kcol);
    kr3 = *(const uint4*)(Kb + (long)(kb + krow + 96) * HD + kcol);
    vr0 = *(const uint4*)(Vb + (long)(vrow) * SLK + kb + vcol);
    vr1 = *(const uint4*)(Vb + (long)(vrow + 16) * SLK + kb + vcol);
    vr2 = *(const uint4*)(Vb + (long)(vrow + 32) * SLK + kb + vcol);
    vr3 = *(const uint4*)(Vb + (long)(vrow + 48) * SLK + kb + vcol);
  }

#pragma unroll
  for (int kt = 0; kt < 4; ++kt) {
    __syncthreads();                    // prev tile's LDS reads done
    *(uint4*)&Kt[(krow) * 72 + kcol] = kr0;
    *(uint4*)&Kt[(krow + 32) * 72 + kcol] = kr1;
    *(uint4*)&Kt[(krow + 64) * 72 + kcol] = kr2;
    *(uint4*)&Kt[(krow + 96) * 72 + kcol] = kr3;
    *(uint4*)&Vl[(vrow) * 136 + vcol] = vr0;
    *(uint4*)&Vl[(vrow + 16) * 136 + vcol] = vr1;
    *(uint4*)&Vl[(vrow + 32) * 136 + vcol] = vr2;
    *(uint4*)&Vl[(vrow + 48) * 136 + vcol] = vr3;
    if (kt < 3) {                       // issue next tile's loads; land during compute
      const int kb = ck * 512 + (kt + 1) * 128;
      kr0 = *(const uint4*)(Kb + (long)(kb + krow) * HD + kcol);
      kr1 = *(const uint4*)(Kb + (long)(kb + krow + 32) * HD + kcol);
      kr2 = *(const uint4*)(Kb + (long)(kb + krow + 64) * HD + kcol);
      kr3 = *(const uint4*)(Kb + (long)(kb + krow + 96) * HD + kcol);
      vr0 = *(const uint4*)(Vb + (long)(vrow) * SLK + kb + vcol);
      vr1 = *(const uint4*)(Vb + (long)(vrow + 16) * SLK + kb + vcol);
      vr2 = *(const uint4*)(Vb + (long)(vrow + 32) * SLK + kb + vcol);
      vr3 = *(const uint4*)(Vb + (long)(vrow + 48) * SLK + kb + vcol);
    }
    __syncthreads();                    // tile visible

    // s[j][r] = S[k = j*16 + quad*4 + r][q = col]   (swapped operands)
    f32x4 s[8];
#pragma unroll
    for (int j = 0; j < 8; ++j) s[j] = (f32x4){0.f, 0.f, 0.f, 0.f};
#pragma unroll
    for (int j = 0; j < 8; ++j)
#pragma unroll
      for (int kk = 0; kk < 2; ++kk) {
        s16x8 bK = *(const s16x8*)&Kt[(j * 16 + col) * 72 + kk * 32 + quad * 8];
        s[j] = __builtin_amdgcn_mfma_f32_16x16x32_bf16(bK, aQ[kk], s[j], 0, 0, 0);
      }
#pragma unroll
    for (int j = 0; j < 8; ++j)
#pragma unroll
      for (int r = 0; r < 4; ++r)
        s[j][r] *= 0.125f;

    float tm = s[0][0];
#pragma unroll
    for (int j = 0; j < 8; ++j)
#pragma unroll
      for (int r = 0; r < 4; ++r)
        tm = fmaxf(tm, s[j][r]);
    tm = fmaxf(tm, __shfl_xor(tm, 16));
    tm = fmaxf(tm, __shfl_xor(tm, 32));
    float mnew = fmaxf(mr, tm);
    float alpha = __expf(mr - mnew);
    mr = mnew;
    float ps = 0.f;
#pragma unroll
    for (int j = 0; j < 8; ++j) {
      float p0 = __expf(s[j][0] - mnew);
      float p1 = __expf(s[j][1] - mnew);
      float p2 = __expf(s[j][2] - mnew);
      float p3 = __expf(s[j][3] - mnew);
      ps += (p0 + p1) + (p2 + p3);
      unsigned int lo = (unsigned int)f2bf(p0) | ((unsigned int)f2bf(p1) << 16);
      unsigned int hi = (unsigned int)f2bf(p2) | ((unsigned int)f2bf(p3) << 16);
      *(uint2*)&Pw[col * 136 + j * 16 + quad * 4] = (uint2){lo, hi};
    }
    ps += __shfl_xor(ps, 16);
    ps += __shfl_xor(ps, 32);
    lr = lr * alpha + ps;

    // broadcast alpha to O's q-rows (rows = quad*4+r, alpha lives at lane q)
    float a0 = __shfl(alpha, quad * 4 + 0);
    float a1 = __shfl(alpha, quad * 4 + 1);
    float a2 = __shfl(alpha, quad * 4 + 2);
    float a3 = __shfl(alpha, quad * 4 + 3);
#pragma unroll
    for (int n = 0; n < 4; ++n) {
      O[n][0] *= a0; O[n][1] *= a1; O[n][2] *= a2; O[n][3] *= a3;
    }
#pragma unroll
    for (int kk = 0; kk < 4; ++kk) {
      s16x8 aP = *(const s16x8*)&Pw[col * 136 + kk * 32 + quad * 8];
#pragma unroll
      for (int n = 0; n < 4; ++n) {
        s16x8 bV = *(const s16x8*)&Vl[(n * 16 + col) * 136 + kk * 32 + quad * 8];
        O[n] = __builtin_amdgcn_mfma_f32_16x16x32_bf16(aP, bV, O[n], 0, 0, 0);
      }
    }
  }

#pragma unroll
  for (int r = 0; r < 4; ++r) {
    int q = qt * 64 + w * 16 + quad * 4 + r;
    long gq = (long)bh * SLQ + q;
#pragma unroll
    for (int n = 0; n < 4; ++n)
      Opart[(gq * 4 + ck) * 64 + n * 16 + col] = f2bf(O[n][r]);
  }
  if (quad == 0) {
    int q = qt * 64 + w * 16 + col;
    ml[((long)bh * SLQ + q) * 4 + ck] = (float2){mr, lr};
  }
}

// merge 4 cross chunks -> attn; also emit global (M, L) stats for the weights pass
__global__ __launch_bounds__(256)
void cross_combine(const u16* __restrict__ Opart, const float2* __restrict__ ml,
                   u16* __restrict__ attn, float2* __restrict__ stat,
                   const int* __restrict__ qlen)
{
  int gr = blockIdx.x * 16 + (threadIdx.x >> 4);
  int bh = gr >> 10, q = gr & 1023;
  int b = bh >> 3, h = bh & 7;
  if (q >= qlen[b]) return;
  int d = (threadIdx.x & 15) * 4;
  long base = (long)gr * 4;
  float M = -1e30f;
#pragma unroll
  for (int c = 0; c < 4; ++c) M = fmaxf(M, ml[base + c].x);
  float L = 0.f;
  float ax = 0.f, ay = 0.f, az = 0.f, aw = 0.f;
#pragma unroll
  for (int c = 0; c < 4; ++c) {
    float2 st = ml[base + c];
    float wgt = __expf(st.x - M);
    L += st.y * wgt;
    const u16* p = Opart + (base + c) * 64 + d;
    ax += bf2f(p[0]) * wgt; ay += bf2f(p[1]) * wgt;
    az += bf2f(p[2]) * wgt; aw += bf2f(p[3]) * wgt;
  }
  if (d == 0) stat[gr] = (float2){M, L};
  float inv = 1.0f / L;
  unsigned int lo = (unsigned int)f2bf(ax * inv) | ((unsigned int)f2bf(ay * inv) << 16);
  unsigned int hi = (unsigned int)f2bf(az * inv) | ((unsigned int)f2bf(aw * inv) << 16);
  *(uint2*)&attn[((long)b * SLQ + q) * EE + h * HD + d] = (uint2){lo, hi};
}

// head-mean attention weights by QK^T recompute.
// block = (key tile of 128, q tile of 64, b); K staged in LDS per head,
// software-pipelined over heads; wave owns 16 q rows x 128 keys.
__global__ __launch_bounds__(256, 4)
void wmean_recompute(const u16* __restrict__ Qc, const u16* __restrict__ Kc,
                     const float2* __restrict__ stat, float* __restrict__ outw,
                     const int* __restrict__ qlen)
{
  const int kt = blockIdx.x;             // 16 key tiles of 128
  const int qt = blockIdx.y;             // 16 q tiles of 64
  const int b  = blockIdx.z;             // 4
  const int qn = qlen[b];
  const int q0 = qt * 64;
  const int t = threadIdx.x, lane = t & 63, w = t >> 6;
  const int col = lane & 15, quad = lane >> 4;

  float* wr = outw + ((long)b * SLQ + q0) * SLK + kt * 128;

  if (q0 >= qn) {
    float4 z = {0.f, 0.f, 0.f, 0.f};
    for (int i = t; i < 64 * 32; i += 256) {
      int row = i >> 5, c = (i & 31) << 2;
      *(float4*)&wr[(long)row * SLK + c] = z;
    }
    return;
  }

  __shared__ __align__(16) u16 Kl[128 * 72];

  const int qw = q0 + w * 16;            // wave's 16 q rows
  const u16* Kbase = Kc + ((long)b * HH * SLK + (long)kt * 128) * HD;

  const int krow = t >> 3, kcol = (t & 7) * 8;

  // preload head 0's K tile into NAMED registers
  uint4 kr0, kr1, kr2, kr3;
  kr0 = *(const uint4*)(Kbase + (long)(krow) * HD + kcol);
  kr1 = *(const uint4*)(Kbase + (long)(krow + 32) * HD + kcol);
  kr2 = *(const uint4*)(Kbase + (long)(krow + 64) * HD + kcol);
  kr3 = *(const uint4*)(Kbase + (long)(krow + 96) * HD + kcol);

  f32x4 acc[8];
#pragma unroll
  for (int j = 0; j < 8; ++j) acc[j] = (f32x4){0.f, 0.f, 0.f, 0.f};

#pragma unroll 1
  for (int h = 0; h < 8; ++h) {
    const int bh = b * 8 + h;
    __syncthreads();                     // previous iteration's LDS reads done
    *(uint4*)&Kl[(krow) * 72 + kcol] = kr0;
    *(uint4*)&Kl[(krow + 32) * 72 + kcol] = kr1;
    *(uint4*)&Kl[(krow + 64) * 72 + kcol] = kr2;
    *(uint4*)&Kl[(krow + 96) * 72 + kcol] = kr3;
    if (h < 7) {
      const u16* Kn = Kbase + (long)(h + 1) * SLK * HD;
      kr0 = *(const uint4*)(Kn + (long)(krow) * HD + kcol);
      kr1 = *(const uint4*)(Kn + (long)(krow + 32) * HD + kcol);
      kr2 = *(const uint4*)(Kn + (long)(krow + 64) * HD + kcol);
      kr3 = *(const uint4*)(Kn + (long)(krow + 96) * HD + kcol);
    }
    const u16* Qb = Qc + ((long)bh * SLQ + qw) * HD;
    s16x8 aQ0 = *(const s16x8*)(Qb + col * HD + quad * 8);
    s16x8 aQ1 = *(const s16x8*)(Qb + col * HD + 32 + quad * 8);
    float m_[4], il_[4];
#pragma unroll
    for (int r = 0; r < 4; ++r) {
      float2 st = stat[(long)bh * SLQ + qw + quad * 4 + r];
      m_[r] = st.x; il_[r] = 0.125f / st.y;
    }
    __syncthreads();                     // K tile visible

    f32x4 s[8];
#pragma unroll
    for (int j = 0; j < 8; ++j) s[j] = (f32x4){0.f, 0.f, 0.f, 0.f};
#pragma unroll
    for (int j = 0; j < 8; ++j) {
      s16x8 bK0 = *(const s16x8*)&Kl[(j * 16 + col) * 72 + quad * 8];
      s16x8 bK1 = *(const s16x8*)&Kl[(j * 16 + col) * 72 + 32 + quad * 8];
      s[j] = __builtin_amdgcn_mfma_f32_16x16x32_bf16(aQ0, bK0, s[j], 0, 0, 0);
      s[j] = __builtin_amdgcn_mfma_f32_16x16x32_bf16(aQ1, bK1, s[j], 0, 0, 0);
    }
#pragma unroll
    for (int j = 0; j < 8; ++j)
#pragma unroll
      for (int r = 0; r < 4; ++r)
        acc[j][r] += __expf(s[j][r] * 0.125f - m_[r]) * il_[r];
  }

#pragma unroll
  for (int r = 0; r < 4; ++r) {
    int row = w * 16 + quad * 4 + r;
    bool v = (q0 + row) < qn;
#pragma unroll
    for (int j = 0; j < 8; ++j)
      wr[(long)row * SLK + j * 16 + col] = v ? acc[j][r] : 0.f;
  }
}

// self-attention: chunk of 256 keys per block (2 tiles, online softmax), bf16 partials.
// SWAPPED QK^T (R6 best config). 1-D grid, XCD-swizzled; named-reg prefetch.
__global__ __launch_bounds__(256, 3)
void self_flash_chunk(const u16* __restrict__ Qc, const u16* __restrict__ Kc,
                      const u16* __restrict__ Vt, u16* __restrict__ Opart,
                      float2* __restrict__ ml, const int* __restrict__ qlen)
{
  const int lin = blockIdx.x;
  const int lid = (lin & 7) * 256 + (lin >> 3);   // bijective: 2048 % 8 == 0
  const int qt = lid & 15;
  const int bh = (lid >> 4) & 31;
  const int ck = lid >> 9;               // 4 chunks of 256
  const int b = bh >> 3;
  const int kmax = qlen[b];
  if (qt * 64 >= kmax || ck * 256 >= kmax) return;

  __shared__ __align__(16) u16 Kt[128 * 72];
  __shared__ __align__(16) u16 Vl[64 * 136];
  __shared__ __align__(16) u16 Pl[4 * 16 * 136];

  const int t = threadIdx.x, lane = t & 63, w = t >> 6;
  const int col = lane & 15, quad = lane >> 4;

  const u16* Qb = Qc + (long)bh * SLQ * HD;
  const u16* Kb = Kc + (long)bh * SLQ * HD;
  const u16* Vb = Vt + (long)bh * HD * SLQ;

  s16x8 aQ[2];
#pragma unroll
  for (int kk = 0; kk < 2; ++kk)
    aQ[kk] = *(const s16x8*)(Qb + (long)(qt * 64 + w * 16 + col) * HD + kk * 32 + quad * 8);

  f32x4 O[4];
#pragma unroll
  for (int n = 0; n < 4; ++n) O[n] = (f32x4){0.f, 0.f, 0.f, 0.f};
  float mr = -1e30f, lr = 0.f;

  u16* Pw = Pl + w * 16 * 136;

  const int krow = t >> 3, kcol = (t & 7) * 8;
  const int vrow = t >> 4, vcol = (t & 15) * 8;

  // prologue: prefetch tile 0 (always within buffer; max addr < SLQ)
  uint4 kr0, kr1, kr2, kr3, vr0, vr1, vr2, vr3;
  {
    const int kb = ck * 256;
    kr0 = *(const uint4*)(Kb + (long)(kb + krow) * HD + kcol);
    kr1 = *(const uint4*)(Kb + (long)(kb + krow + 32) * HD + kcol);
    kr2 = *(const uint4*)(Kb + (long)(kb + krow + 64) * HD + kcol);
    kr3 = *(const uint4*)(Kb + (long)(kb + krow + 96) * HD + kcol);
    vr0 = *(const uint4*)(Vb + (long)(vrow) * SLQ + kb + vcol);
    vr1 = *(const uint4*)(Vb + (long)(vrow + 16) * SLQ + kb + vcol);
    vr2 = *(const uint4*)(Vb + (long)(vrow + 32) * SLQ + kb + vcol);
    vr3 = *(const uint4*)(Vb + (long)(vrow + 48) * SLQ + kb + vcol);
  }

#pragma unroll
  for (int kt = 0; kt < 2; ++kt) {
    const int k0 = ck * 256 + kt * 128;
    if (k0 >= kmax) break;               // block-uniform
    __syncthreads();
    *(uint4*)&Kt[(krow) * 72 + kcol] = kr0;
    *(uint4*)&Kt[(krow + 32) * 72 + kcol] = kr1;
    *(uint4*)&Kt[(krow + 64) * 72 + kcol] = kr2;
    *(uint4*)&Kt[(krow + 96) * 72 + kcol] = kr3;
    *(uint4*)&Vl[(vrow) * 136 + vcol] = vr0;
    *(uint4*)&Vl[(vrow + 16) * 136 + vcol] = vr1;
    *(uint4*)&Vl[(vrow + 32) * 136 + vcol] = vr2;
    *(uint4*)&Vl[(vrow + 48) * 136 + vcol] = vr3;
    if (kt < 1) {
      const int kb = ck * 256 + 128;     // in-bounds (max 896+127 < 1024)
      kr0 = *(const uint4*)(Kb + (long)(kb + krow) * HD + kcol);
      kr1 = *(const uint4*)(Kb + (long)(kb + krow + 32) * HD + kcol);
      kr2 = *(const uint4*)(Kb + (long)(kb + krow + 64) * HD + kcol);
      kr3 = *(const uint4*)(Kb + (long)(kb + krow + 96) * HD + kcol);
      vr0 = *(const uint4*)(Vb + (long)(vrow) * SLQ + kb + vcol);
      vr1 = *(const uint4*)(Vb + (long)(vrow + 16) * SLQ + kb + vcol);
      vr2 = *(const uint4*)(Vb + (long)(vrow + 32) * SLQ + kb + vcol);
      vr3 = *(const uint4*)(Vb + (long)(vrow + 48) * SLQ + kb + vcol);
    }
    __syncthreads();

    // s[j][r] = S[k = k0 + j*16 + quad*4 + r][q = col]
    f32x4 s[8];
#pragma unroll
    for (int j = 0; j < 8; ++j) s[j] = (f32x4){0.f, 0.f, 0.f, 0.f};
#pragma unroll
    for (int j = 0; j < 8; ++j)
#pragma unroll
      for (int kk = 0; kk < 2; ++kk) {
        s16x8 bK = *(const s16x8*)&Kt[(j * 16 + col) * 72 + kk * 32 + quad * 8];
        s[j] = __builtin_amdgcn_mfma_f32_16x16x32_bf16(bK, aQ[kk], s[j], 0, 0, 0);
      }
#pragma unroll
    for (int j = 0; j < 8; ++j)
#pragma unroll
      for (int r = 0; r < 4; ++r) {
        bool ok = (k0 + j * 16 + quad * 4 + r) < kmax;
        s[j][r] = ok ? s[j][r] * 0.125f : -1e30f;
      }

    float tm = s[0][0];
#pragma unroll
    for (int j = 0; j < 8; ++j)
#pragma unroll
      for (int r = 0; r < 4; ++r)
        tm = fmaxf(tm, s[j][r]);
    tm = fmaxf(tm, __shfl_xor(tm, 16));
    tm = fmaxf(tm, __shfl_xor(tm, 32));
    float mnew = fmaxf(mr, tm);
    float alpha = __expf(mr - mnew);
    mr = mnew;
    float ps = 0.f;
#pragma unroll
    for (int j = 0; j < 8; ++j) {
      float p0 = __expf(s[j][0] - mnew);
      float p1 = __expf(s[j][1] - mnew);
      float p2 = __expf(s[j][2] - mnew);
      float p3 = __expf(s[j][3] - mnew);
      ps += (p0 + p1) + (p2 + p3);
      unsigned int lo = (unsigned int)f2bf(p0) | ((unsigned int)f2bf(p1) << 16);
      unsigned int hi = (unsigned int)f2bf(p2) | ((unsigned int)f2bf(p3) << 16);
      *(uint2*)&Pw[col * 136 + j * 16 + quad * 4] = (uint2){lo, hi};
    }
    ps += __shfl_xor(ps, 16);
    ps += __shfl_xor(ps, 32);
    lr = lr * alpha + ps;

    float a0 = __shfl(alpha, quad * 4 + 0);
    float a1 = __shfl(alpha, quad * 4 + 1);
    float a2 = __shfl(alpha, quad * 4 + 2);
    float a3 = __shfl(alpha, quad * 4 + 3);
#pragma unroll
    for (int n = 0; n < 4; ++n) {
      O[n][0] *= a0; O[n][1] *= a1; O[n][2] *= a2; O[n][3] *= a3;
    }
#pragma unroll
    for (int kk = 0; kk < 4; ++kk) {
      s16x8 aP = *(const s16x8*)&Pw[col * 136 + kk * 32 + quad * 8];
#pragma unroll
      for (int n = 0; n < 4; ++n) {
        s16x8 bV = *(const s16x8*)&Vl[(n * 16 + col) * 136 + kk * 32 + quad * 8];
        O[n] = __builtin_amdgcn_mfma_f32_16x16x32_bf16(aP, bV, O[n], 0, 0, 0);
      }
    }
  }

#pragma unroll
  for (int r = 0; r < 4; ++r) {
    int q = qt * 64 + w * 16 + quad * 4 + r;
    long gq = (long)bh * SLQ + q;
#pragma unroll
    for (int n = 0; n < 4; ++n)
      Opart[(gq * 4 + ck) * 64 + n * 16 + col] = f2bf(O[n][r]);
  }
  if (quad == 0) {
    int q = qt * 64 + w * 16 + col;
    ml[((long)bh * SLQ + q) * 4 + ck] = (float2){mr, lr};
  }
}

__global__ __launch_bounds__(256)
void self_combine(const u16* __restrict__ Opart, const float2* __restrict__ ml,
                  u16* __restrict__ attn, const int* __restrict__ qlen)
{
  int gr = blockIdx.x * 16 + (threadIdx.x >> 4);
  int bh = gr >> 10, q = gr & 1023;
  int b = bh >> 3, h = bh & 7;
  int kmax = qlen[b];
  if (q >= kmax) return;
  int NC = (kmax + 255) >> 8;
  int d = (threadIdx.x & 15) * 4;
  long base = (long)gr * 4;
  float M = -1e30f;
  for (int c = 0; c < NC; ++c) M = fmaxf(M, ml[base + c].x);
  float L = 0.f;
  float ax = 0.f, ay = 0.f, az = 0.f, aw = 0.f;
  for (int c = 0; c < NC; ++c) {
    float2 st = ml[base + c];
    float wgt = __expf(st.x - M);
    L += st.y * wgt;
    const u16* p = Opart + (base + c) * 64 + d;
    ax += bf2f(p[0]) * wgt; ay += bf2f(p[1]) * wgt;
    az += bf2f(p[2]) * wgt; aw += bf2f(p[3]) * wgt;
  }
  float inv = 1.0f / L;
  unsigned int lo = (unsigned int)f2bf(ax * inv) | ((unsigned int)f2bf(ay * inv) << 16);
  unsigned int hi = (unsigned int)f2bf(az * inv) | ((unsigned int)f2bf(aw * inv) << 16);
  *(uint2*)&attn[((long)b * SLQ + q) * EE + h * HD + d] = (uint2){lo, hi};
}

// fused input conversion: masked queries + keys + 9 weight matrices
__global__ __launch_bounds__(256)
void cvt_all(const float* __restrict__ queries, const float* __restrict__ keys,
             const int* __restrict__ qlen,
             const float* w0, const float* w1, const float* w2, const float* w3,
             const float* w4, const float* w5, const float* w6, const float* w7,
             const float* w8,
             u16* __restrict__ q0, u16* __restrict__ keysb, u16* __restrict__ Wb) {
  int blk = blockIdx.x;
  int t = threadIdx.x;
  const float* src;
  u16* dst;
  long off;
  bool mask = false;
  int b = 0, q = 0;
  if (blk < 1024) {
    off = (long)blk * 2048 + t * 8;
    int row = (int)(off >> 9);
    b = row >> 10; q = row & 1023;
    mask = true;
    src = queries; dst = q0;
  } else if (blk < 3072) {
    off = (long)(blk - 1024) * 2048 + t * 8;
    src = keys; dst = keysb;
  } else {
    int mat = (blk - 3072) >> 7, part = (blk - 3072) & 127;
    const float* srcs[9] = {w0, w1, w2, w3, w4, w5, w6, w7, w8};
    src = srcs[mat];
    off = (long)part * 2048 + t * 8;
    dst = Wb + (long)mat * EE * EE;
  }
  s16x8 o = (s16x8){0, 0, 0, 0, 0, 0, 0, 0};
  if (!mask || q < qlen[b]) {
    float4 a = *(const float4*)&src[off];
    float4 c = *(const float4*)&src[off + 4];
    o[0] = (short)f2bf(a.x); o[1] = (short)f2bf(a.y);
    o[2] = (short)f2bf(a.z); o[3] = (short)f2bf(a.w);
    o[4] = (short)f2bf(c.x); o[5] = (short)f2bf(c.y);
    o[6] = (short)f2bf(c.z); o[7] = (short)f2bf(c.w);
  }
  *(s16x8*)&dst[off] = o;
}

__device__ __forceinline__ float blockSum(float v, float* red4) {
#pragma unroll
  for (int o = 32; o; o >>= 1) v += __shfl_xor(v, o);
  if ((threadIdx.x & 63) == 0) red4[threadIdx.x >> 6] = v;
  __syncthreads();
  v = red4[0] + red4[1] + red4[2] + red4[3];
  __syncthreads();
  return v;
}

template<int OUTF32>
__global__ __launch_bounds__(256)
void silu_ln_kernel(const u16* __restrict__ x1, const u16* __restrict__ x2,
                    const float* __restrict__ g, const float* __restrict__ beta,
                    const int* __restrict__ qlen, void* __restrict__ outv, int mode) {
  int row = blockIdx.x;
  int b = row >> 10, q = row & 1023;
  int t = threadIdx.x;
  if (mode && q >= qlen[b]) {
    if (mode == 1) {
      if (OUTF32) {
        float* o = (float*)outv + (long)row * EE;
        o[2 * t] = 0.f; o[2 * t + 1] = 0.f;
      } else {
        u16* o = (u16*)outv + (long)row * EE;
        *(unsigned int*)&o[2 * t] = 0u;
      }
    }
    return;
  }
  __shared__ float red4[4];
  const u16* p1 = x1 + (long)row * EE;
  const u16* p2 = x2 + (long)row * EE;
  float a0 = bf2f(p1[2 * t]) + bf2f(p2[2 * t]);
  float a1 = bf2f(p1[2 * t + 1]) + bf2f(p2[2 * t + 1]);
  a0 = a0 / (1.f + __expf(-a0));
  a1 = a1 / (1.f + __expf(-a1));
  float mu = blockSum(a0 + a1, red4) * (1.f / 512.f);
  float d0 = a0 - mu, d1 = a1 - mu;
  float var = blockSum(d0 * d0 + d1 * d1, red4) * (1.f / 512.f);
  float rs = rsqrtf(var + 1e-5f);
  float r0 = d0 * rs * g[2 * t] + beta[2 * t];
  float r1 = d1 * rs * g[2 * t + 1] + beta[2 * t + 1];
  if (OUTF32) {
    float* o = (float*)outv + (long)row * EE;
    o[2 * t] = r0; o[2 * t + 1] = r1;
  } else {
    u16* o = (u16*)outv + (long)row * EE;
    o[2 * t] = f2bf(r0); o[2 * t + 1] = f2bf(r1);
  }
}

extern "C" void kernel_launch(void* const* d_in, const int* in_sizes, int n_in,
                              void* d_out, int out_size, void* d_ws, size_t ws_size,
                              hipStream_t stream) {
  const float* queries = (const float*)d_in[0];
  const float* keys    = (const float*)d_in[1];
  const int*   qlen    = (const int*)d_in[2];
  const float* cWq = (const float*)d_in[3],  *cbq = (const float*)d_in[4];
  const float* cWk = (const float*)d_in[5],  *cbk = (const float*)d_in[6];
  const float* cWv = (const float*)d_in[7],  *cbv = (const float*)d_in[8];
  const float* cWo = (const float*)d_in[9],  *cbo = (const float*)d_in[10];
  const float* sWq = (const float*)d_in[11], *sbq = (const float*)d_in[12];
  const float* sWk = (const float*)d_in[13], *sbk = (const float*)d_in[14];
  const float* sWv = (const float*)d_in[15], *sbv = (const float*)d_in[16];
  const float* sWo = (const float*)d_in[17], *sbo = (const float*)d_in[18];
  const float* Wf  = (const float*)d_in[19], *bfb = (const float*)d_in[20];
  const float* g_cross = (const float*)d_in[21], *b_cross = (const float*)d_in[22];
  const float* g_ffn   = (const float*)d_in[23], *b_ffn   = (const float*)d_in[24];
  const float* g_self  = (const float*)d_in[25], *b_self  = (const float*)d_in[26];

  float* out_q = (float*)d_out;
  float* out_w = out_q + (long)BB * SLQ * EE;

  u16* ws = (u16*)d_ws;
  u16* S     = ws;                               // region kept for layout; cross S no longer materialized
  u16* Qc    = S   + (long)BB * HH * SLQ * SLK;
  u16* Kc    = Qc  + (long)BB * HH * SLQ * HD;
  u16* Vt    = Kc  + (long)BB * HH * SLK * HD;
  u16* q0    = Vt  + (long)BB * HH * SLK * HD;
  u16* keysb = q0  + (long)BB * SLQ * EE;
  u16* attn  = keysb + (long)BB * SLK * EE;
  u16* proj  = attn + (long)BB * SLQ * EE;
  u16* q1    = proj + (long)BB * SLQ * EE;
  u16* fbuf  = q1  + (long)BB * SLQ * EE;
  u16* q2    = fbuf + (long)BB * SLQ * EE;
  u16* Wb    = q2  + (long)BB * SLQ * EE;
  const long WSLOT = (long)EE * EE;
  u16*    Cpb  = Wb + 9 * WSLOT;                  // cross O partials bf16: 32768*4*64
  float2* stat = (float2*)(Cpb + 8388608);        // 32768 float2 (M, L)

  // cross flash ml lives in the (now dead) S region, clear of the self overlay below
  float2* mlC = (float2*)(S + 33554432);          // 32768*4 float2

  // self partials overlay S (front of region)
  u16*    OpS = S;                                // 32768*4*64 bf16
  float2* mlS = (float2*)(S + 8388608);           // 32768*4 float2

  u16* bWq = Wb + 0 * WSLOT; u16* bWk = Wb + 1 * WSLOT; u16* bWv = Wb + 2 * WSLOT;
  u16* bWo = Wb + 3 * WSLOT; u16* bsWq = Wb + 4 * WSLOT; u16* bsWk = Wb + 5 * WSLOT;
  u16* bsWv = Wb + 6 * WSLOT; u16* bsWo = Wb + 7 * WSLOT; u16* bWf = Wb + 8 * WSLOT;

  dim3 blk(256);
  const int MQ = BB * SLQ;   // 4096
  const int MK = BB * SLK;   // 8192

  cvt_all<<<dim3(3072 + 9 * 128), blk, 0, stream>>>(
      queries, keys, qlen, cWq, cWk, cWv, cWo, sWq, sWk, sWv, sWo, Wf, q0, keysb, Wb);

  // cross Q projection (64^2: qlen-skip leaves ~288 of 512 blocks -> keep small tile)
  gemm_nt<64, 64, 1, 2><<<dim3(EE / 64, MQ / 64, 1), blk, 0, stream>>>(
      q0, bWq, cbq, Qc, MQ, EE, EE, EE, EE, 0, 0, 0, 0, 1.0f, SLQ, qlen);
  // cross K+V projections in one dispatch (128x64: no skip, 1024 blocks)
  gemm_proj<128, 64, 0, 2><<<dim3(EE / 64, MK / 128, 2), blk, 0, stream>>>(
      keysb, bWk, bWv, nullptr, cbk, cbv, nullptr, Kc, Vt, nullptr, MK, EE, SLK, qlen);

  // fused cross attention: no S materialization (1-D swizzled grid)
  cross_flash_chunk<<<dim3(2048), blk, 0, stream>>>(Qc, Kc, Vt, Cpb, mlC, qlen);
  cross_combine<<<dim3(2048), blk, 0, stream>>>(Cpb, mlC, attn, stat, qlen);
  // head-mean attention weights via QK^T recompute (LDS-staged, head-pipelined)
  wmean_recompute<<<dim3(16, 16, BB), blk, 0, stream>>>(Qc, Kc, stat, out_w, qlen);

  gemm_nt<64, 64, 0, 2><<<dim3(EE / 64, MQ / 64, 1), blk, 0, stream>>>(
      attn, bWo, cbo, proj, MQ, EE, EE, EE, EE, EE, 0, 0, 0, 1.0f, SLQ, qlen);

  silu_ln_kernel<0><<<dim3(MQ), blk, 0, stream>>>(proj, q0, g_cross, b_cross, qlen, q1, 2);

  gemm_nt<64, 64, 0, 2><<<dim3(EE / 64, MQ / 64, 1), blk, 0, stream>>>(
      q1, bWf, bfb, fbuf, MQ, EE, EE, EE, EE, EE, 0, 0, 0, 1.0f, SLQ, qlen);

  silu_ln_kernel<0><<<dim3(MQ), blk, 0, stream>>>(q1, fbuf, g_ffn, b_ffn, qlen, q2, 1);

  // self Q/K/V projections in one dispatch (128x64: ~432 surviving blocks)
  gemm_proj<128, 64, 2, 3><<<dim3(EE / 64, MQ / 128, 3), blk, 0, stream>>>(
      q2, bsWq, bsWk, bsWv, sbq, sbk, sbv, Qc, Kc, Vt, MQ, EE, SLQ, qlen);

  // fused self attention (partials overlay S; 1-D swizzled grid)
  self_flash_chunk<<<dim3(2048), blk, 0, stream>>>(Qc, Kc, Vt, OpS, mlS, qlen);
  self_combine<<<dim3(2048), blk, 0, stream>>>(OpS, mlS, attn, qlen);

  gemm_nt<64, 64, 0, 2><<<dim3(EE / 64, MQ / 64, 1), blk, 0, stream>>>(
      attn, bsWo, sbo, proj, MQ, EE, EE, EE, EE, EE, 0, 0, 0, 1.0f, SLQ, qlen);

  silu_ln_kernel<1><<<dim3(MQ), blk, 0, stream>>>(q2, proj, g_self, b_self, qlen, out_q, 1);
}

// Round 12
// 290.949 us; speedup vs baseline: 1.2621x; 1.0150x over previous
//
#include <hip/hip_runtime.h>

#define BB 4
#define SLQ 1024
#define SLK 2048
#define EE 512
#define HH 8
#define HD 64

typedef unsigned short u16;
typedef __attribute__((ext_vector_type(8))) short s16x8;
typedef __attribute__((ext_vector_type(4))) float f32x4;

__device__ __forceinline__ float bf2f(u16 u) {
  union { unsigned int i; float f; } v; v.i = ((unsigned int)u) << 16; return v.f;
}
__device__ __forceinline__ u16 f2bf(float f) {
  union { float f; unsigned int i; } v; v.f = f;
  unsigned int i = v.i;
  return (u16)((i + 0x7fffu + ((i >> 16) & 1u)) >> 16);
}
// packed f32 pair -> 2x bf16 (RNE) in one instruction (no builtin on gfx950)
__device__ __forceinline__ unsigned int cvt_pk_bf16(float lo, float hi) {
  unsigned int r;
  asm("v_cvt_pk_bf16_f32 %0, %1, %2" : "=v"(r) : "v"(lo), "v"(hi));
  return r;
}

__device__ __forceinline__ void async16(const u16* g, u16* l) {
  __builtin_amdgcn_global_load_lds(
      (const __attribute__((address_space(1))) unsigned int*)g,
      (__attribute__((address_space(3))) unsigned int*)l, 16, 0, 0);
}

// NT GEMM: C[m,n] = alpha*sum_k A[m,k]*B[n,k] + bias[n]
// MODE 0: row-major, per-wave barrier-free staged write
// MODE 1: head-split [B,H,Lsub,64] direct scatter
// SKIPQ 0: none; 1: b=z>>3, skip tileM>=qlen[b]; 2: b=tileM>>10 (Lsub=1024)
template<int BM, int BN, int MODE, int SKIPQ>
__global__ __launch_bounds__(256, (BM == 128 ? 4 : 6))
void gemm_nt(const u16* __restrict__ A, const u16* __restrict__ Bm,
             const float* __restrict__ bias, u16* __restrict__ C,
             int M, int N, int K, int lda, int ldb, int ldc,
             long sAz, long sBz, long sCz, float alpha, int Lsub,
             const int* __restrict__ qlen)
{
  constexpr int WTM = BM / 2, WTN = BN / 2;
  constexpr int MI = WTM / 16, NI = WTN / 16;
  constexpr int EPAD = WTN + 8;
  constexpr int SM1 = (BM + BN) * 32;
  constexpr int SM2 = (MODE == 0) ? 4 * WTM * EPAD : 0;
  constexpr int SM = (SM1 > SM2) ? SM1 : SM2;

  const int z = blockIdx.z;
  const int tileM = blockIdx.y * BM;
  const int tileN = blockIdx.x * BN;

  if (SKIPQ == 1) { if (tileM >= qlen[z >> 3]) return; }
  if (SKIPQ == 2) { int b = tileM >> 10; if ((tileM & 1023) >= qlen[b]) return; }

  __shared__ __align__(16) u16 smem[SM];
  u16* ldsA = smem;
  u16* ldsB = smem + BM * 32;

  const int t = threadIdx.x;
  const int lane = t & 63;
  const int wave = t >> 6;
  const int waveM = wave >> 1;
  const int waveN = wave & 1;
  const int lm = lane & 15;
  const int kg = lane >> 4;

  const u16* Ab = A + (long)z * sAz + (long)tileM * lda;
  const u16* Bb = Bm + (long)z * sBz + (long)tileN * ldb;

  f32x4 acc[MI][NI];
#pragma unroll
  for (int i = 0; i < MI; ++i)
#pragma unroll
    for (int j = 0; j < NI; ++j) acc[i][j] = (f32x4){0.f, 0.f, 0.f, 0.f};

  for (int kt = 0; kt < K; kt += 32) {
    __syncthreads();
#pragma unroll
    for (int i = 0; i < (BM * 4) / 256; ++i) {
      int c = i * 256 + t;
      async16(Ab + (long)(c >> 2) * lda + kt + (c & 3) * 8, ldsA + (c - lane) * 8);
    }
#pragma unroll
    for (int i = 0; i < (BN * 4) / 256; ++i) {
      int c = i * 256 + t;
      async16(Bb + (long)(c >> 2) * ldb + kt + (c & 3) * 8, ldsB + (c - lane) * 8);
    }
    __syncthreads();

    s16x8 aF[MI], bF[NI];
#pragma unroll
    for (int i = 0; i < MI; ++i)
      aF[i] = *(const s16x8*)&ldsA[(waveM * WTM + i * 16 + lm) * 32 + kg * 8];
#pragma unroll
    for (int j = 0; j < NI; ++j)
      bF[j] = *(const s16x8*)&ldsB[(waveN * WTN + j * 16 + lm) * 32 + kg * 8];
#pragma unroll
    for (int i = 0; i < MI; ++i)
#pragma unroll
      for (int j = 0; j < NI; ++j)
        acc[i][j] = __builtin_amdgcn_mfma_f32_16x16x32_bf16(aF[i], bF[j], acc[i][j], 0, 0, 0);
  }

  if (MODE == 0) {
    // per-wave staged write: no cross-wave barriers in the store phase
    u16* ep = smem + wave * (WTM * EPAD);
    __syncthreads();
#pragma unroll
    for (int i = 0; i < MI; ++i)
#pragma unroll
      for (int j = 0; j < NI; ++j) {
        int n = waveN * WTN + j * 16 + lm;
        float bv = bias ? bias[tileN + n] : 0.0f;
#pragma unroll
        for (int r = 0; r < 4; ++r)
          ep[(i * 16 + kg * 4 + r) * EPAD + j * 16 + lm] = f2bf(acc[i][j][r] * alpha + bv);
      }
    const long Crow = (long)z * sCz + (long)(tileM + waveM * WTM) * ldc + tileN + waveN * WTN;
#pragma unroll
    for (int it = 0; it < (WTM * WTN) / 512; ++it) {
      int idx = it * 64 + lane;
      int row = idx / (WTN / 8), seg = idx % (WTN / 8);
      *(uint4*)&C[Crow + (long)row * ldc + seg * 8] =
          *(const uint4*)&ep[row * EPAD + seg * 8];
    }
  } else {
#pragma unroll
    for (int j = 0; j < NI; ++j) {
      int n = tileN + waveN * WTN + j * 16 + lm;
      float bv = bias ? bias[n] : 0.0f;
#pragma unroll
      for (int i = 0; i < MI; ++i) {
#pragma unroll
        for (int r = 0; r < 4; ++r) {
          int m = tileM + waveM * WTM + i * 16 + kg * 4 + r;
          float v = acc[i][j][r] * alpha + bv;
          int b = m / Lsub, l = m - b * Lsub;
          int h = n >> 6, d = n & 63;
          C[(((long)(b * HH + h) * Lsub + l) << 6) + d] = f2bf(v);
        }
      }
    }
  }
}

// multi-projection: z selects weight/bias/output; z<NPROJ-1 -> head-split [B,H,L,64],
// z==NPROJ-1 -> transposed [B,H,64,L] staged write. K = EE, N = EE.
template<int BM, int BN, int SKIPQ, int NPROJ>
__global__ __launch_bounds__(256, (BM == 128 ? 4 : 6))
void gemm_proj(const u16* __restrict__ A,
               const u16* B0, const u16* B1, const u16* B2,
               const float* bias0, const float* bias1, const float* bias2,
               u16* C0, u16* C1, u16* C2,
               int M, int lda, int Lsub, const int* __restrict__ qlen)
{
  constexpr int WTM = BM / 2, WTN = BN / 2;
  constexpr int MI = WTM / 16, NI = WTN / 16;

  const int z = blockIdx.z;
  const int tileM = blockIdx.y * BM;
  const int tileN = blockIdx.x * BN;
  if (SKIPQ == 2) { int b = tileM >> 10; if ((tileM & 1023) >= qlen[b]) return; }

  const u16* Bm = (z == 0) ? B0 : (z == 1) ? B1 : B2;
  const float* bias = (z == 0) ? bias0 : (z == 1) ? bias1 : bias2;
  u16* C = (z == 0) ? C0 : (z == 1) ? C1 : C2;
  const bool tr = (z == NPROJ - 1);

  __shared__ __align__(16) u16 smem[(BM + BN) * 32];
  u16* ldsA = smem;
  u16* ldsB = smem + BM * 32;

  const int t = threadIdx.x;
  const int lane = t & 63;
  const int wave = t >> 6;
  const int waveM = wave >> 1;
  const int waveN = wave & 1;
  const int lm = lane & 15;
  const int kg = lane >> 4;

  const u16* Ab = A + (long)tileM * lda;
  const u16* Bb = Bm + (long)tileN * EE;

  f32x4 acc[MI][NI];
#pragma unroll
  for (int i = 0; i < MI; ++i)
#pragma unroll
    for (int j = 0; j < NI; ++j) acc[i][j] = (f32x4){0.f, 0.f, 0.f, 0.f};

  for (int kt = 0; kt < EE; kt += 32) {
    __syncthreads();
#pragma unroll
    for (int i = 0; i < (BM * 4) / 256; ++i) {
      int c = i * 256 + t;
      async16(Ab + (long)(c >> 2) * lda + kt + (c & 3) * 8, ldsA + (c - lane) * 8);
    }
#pragma unroll
    for (int i = 0; i < (BN * 4) / 256; ++i) {
      int c = i * 256 + t;
      async16(Bb + (long)(c >> 2) * EE + kt + (c & 3) * 8, ldsB + (c - lane) * 8);
    }
    __syncthreads();

    s16x8 aF[MI], bF[NI];
#pragma unroll
    for (int i = 0; i < MI; ++i)
      aF[i] = *(const s16x8*)&ldsA[(waveM * WTM + i * 16 + lm) * 32 + kg * 8];
#pragma unroll
    for (int j = 0; j < NI; ++j)
      bF[j] = *(const s16x8*)&ldsB[(waveN * WTN + j * 16 + lm) * 32 + kg * 8];
#pragma unroll
    for (int i = 0; i < MI; ++i)
#pragma unroll
      for (int j = 0; j < NI; ++j)
        acc[i][j] = __builtin_amdgcn_mfma_f32_16x16x32_bf16(aF[i], bF[j], acc[i][j], 0, 0, 0);
  }

  if (!tr) {
#pragma unroll
    for (int j = 0; j < NI; ++j) {
      int n = tileN + waveN * WTN + j * 16 + lm;
      float bv = bias[n];
#pragma unroll
      for (int i = 0; i < MI; ++i)
#pragma unroll
        for (int r = 0; r < 4; ++r) {
          int m = tileM + waveM * WTM + i * 16 + kg * 4 + r;
          int b = m / Lsub, l = m - b * Lsub;
          int h = n >> 6, d = n & 63;
          C[(((long)(b * HH + h) * Lsub + l) << 6) + d] = f2bf(acc[i][j][r] + bv);
        }
    }
  } else {
    constexpr int PAD = BM + 8;
    const int bb = tileM / Lsub;
    const int l0 = tileM - bb * Lsub;
#pragma unroll
    for (int c = 0; c < BN / 32; ++c) {
      __syncthreads();
#pragma unroll
      for (int j = 0; j < NI; ++j) {
        int nloc = waveN * WTN + j * 16 + lm;
        if (nloc >= c * 32 && nloc < c * 32 + 32) {
          int nl = nloc - c * 32;
          float bv = bias[tileN + nloc];
#pragma unroll
          for (int i = 0; i < MI; ++i)
#pragma unroll
            for (int r = 0; r < 4; ++r) {
              int mm = waveM * WTM + i * 16 + kg * 4 + r;
              smem[nl * PAD + mm] = f2bf(acc[i][j][r] + bv);
            }
        }
      }
      __syncthreads();
#pragma unroll
      for (int v = 0; v < (32 * BM) / (256 * 8); ++v) {
        int idx = v * 256 + t;
        int nl = idx / (BM / 8), m8 = idx % (BM / 8);
        int n = tileN + c * 32 + nl;
        int h = n >> 6, d = n & 63;
        *(uint4*)&C[((long)(bb * HH + h) * HD + d) * Lsub + l0 + m8 * 8] =
            *(const uint4*)&smem[nl * PAD + m8 * 8];
      }
    }
  }
}

// cross flash attention: chunk of 512 keys per block (4 tiles, online softmax),
// bf16 partials. SWAPPED QK^T; defer-max (skip O-rescale when max growth <= 8);
// v_cvt_pk_bf16_f32 P-store. 1-D grid 2048, XCD-swizzled; named-reg prefetch.
__global__ __launch_bounds__(256, 3)
void cross_flash_chunk(const u16* __restrict__ Qc, const u16* __restrict__ Kc,
                       const u16* __restrict__ Vt, u16* __restrict__ Opart,
                       float2* __restrict__ ml, const int* __restrict__ qlen)
{
  const int lin = blockIdx.x;
  const int lid = (lin & 7) * 256 + (lin >> 3);   // bijective: 2048 % 8 == 0
  const int qt = lid & 15;              // 16 q-tiles of 64
  const int bh = (lid >> 4) & 31;       // 32
  const int ck = lid >> 9;              // 4 chunks of 512 keys
  const int b = bh >> 3;
  if (qt * 64 >= qlen[b]) return;

  __shared__ __align__(16) u16 Kt[128 * 72];
  __shared__ __align__(16) u16 Vl[64 * 136];
  __shared__ __align__(16) u16 Pl[4 * 16 * 136];

  const int t = threadIdx.x, lane = t & 63, w = t >> 6;
  const int col = lane & 15, quad = lane >> 4;

  const u16* Qb = Qc + (long)bh * SLQ * HD;
  const u16* Kb = Kc + (long)bh * SLK * HD;
  const u16* Vb = Vt + (long)bh * HD * SLK;

  s16x8 aQ[2];
#pragma unroll
  for (int kk = 0; kk < 2; ++kk)
    aQ[kk] = *(const s16x8*)(Qb + (long)(qt * 64 + w * 16 + col) * HD + kk * 32 + quad * 8);

  f32x4 O[4];
#pragma unroll
  for (int n = 0; n < 4; ++n) O[n] = (f32x4){0.f, 0.f, 0.f, 0.f};
  float mr = -1e30f, lr = 0.f;         // per-lane softmax state for q = col

  u16* Pw = Pl + w * 16 * 136;

  const int krow = t >> 3, kcol = (t & 7) * 8;   // K stage: 128 rows x 64 cols
  const int vrow = t >> 4, vcol = (t & 15) * 8;  // V stage: 64 rows x 128 cols

  // prologue: prefetch tile 0 K/V into NAMED registers (no arrays -> no scratch)
  uint4 kr0, kr1, kr2, kr3, vr0, vr1, vr2, vr3;
  {
    const int kb = ck * 512;
    kr0 = *(const uint4*)(Kb + (long)(kb + krow) * HD + kcol);
    kr1 = *(const uint4*)(Kb + (long)(kb + krow + 32) * HD + kcol);
    kr2 = *(const uint4*)(Kb + (long)(kb + krow + 64) * HD + kcol);
    kr3 = *(const uint4*)(Kb + (long)(kb + krow + 96) * HD + kcol);
    vr0 = *(const uint4*)(Vb + (long)(vrow) * SLK + kb + vcol);
    vr1 = *(const uint4*)(Vb + (long)(vrow + 16) * SLK + kb + vcol);
    vr2 = *(const uint4*)(Vb + (long)(vrow + 32) * SLK + kb + vcol);
    vr3 = *(const uint4*)(Vb + (long)(vrow + 48) * SLK + kb + vcol);
  }

#pragma unroll
  for (int kt = 0; kt < 4; ++kt) {
    __syncthreads();                    // prev tile's LDS reads done
    *(uint4*)&Kt[(krow) * 72 + kcol] = kr0;
    *(uint4*)&Kt[(krow + 32) * 72 + kcol] = kr1;
    *(uint4*)&Kt[(krow + 64) * 72 + kcol] = kr2;
    *(uint4*)&Kt[(krow + 96) * 72 + kcol] = kr3;
    *(uint4*)&Vl[(vrow) * 136 + vcol] = vr0;
    *(uint4*)&Vl[(vrow + 16) * 136 + vcol] = vr1;
    *(uint4*)&Vl[(vrow + 32) * 136 + vcol] = vr2;
    *(uint4*)&Vl[(vrow + 48) * 136 + vcol] = vr3;
    if (kt < 3) {                       // issue next tile's loads; land during compute
      const int kb = ck * 512 + (kt + 1) * 128;
      kr0 = *(const uint4*)(Kb + (long)(kb + krow) * HD + kcol);
      kr1 = *(const uint4*)(Kb + (long)(kb + krow + 32) * HD + kcol);
      kr2 = *(const uint4*)(Kb + (long)(kb + krow + 64) * HD + kcol);
      kr3 = *(const uint4*)(Kb + (long)(kb + krow + 96) * HD + kcol);
      vr0 = *(const uint4*)(Vb + (long)(vrow) * SLK + kb + vcol);
      vr1 = *(const uint4*)(Vb + (long)(vrow + 16) * SLK + kb + vcol);
      vr2 = *(const uint4*)(Vb + (long)(vrow + 32) * SLK + kb + vcol);
      vr3 = *(const uint4*)(Vb + (long)(vrow + 48) * SLK + kb + vcol);
    }
    __syncthreads();                    // tile visible

    // s[j][r] = S[k = j*16 + quad*4 + r][q = col]   (swapped operands)
    f32x4 s[8];
#pragma unroll
    for (int j = 0; j < 8; ++j) s[j] = (f32x4){0.f, 0.f, 0.f, 0.f};
#pragma unroll
    for (int j = 0; j < 8; ++j)
#pragma unroll
      for (int kk = 0; kk < 2; ++kk) {
        s16x8 bK = *(const s16x8*)&Kt[(j * 16 + col) * 72 + kk * 32 + quad * 8];
        s[j] = __builtin_amdgcn_mfma_f32_16x16x32_bf16(bK, aQ[kk], s[j], 0, 0, 0);
      }
#pragma unroll
    for (int j = 0; j < 8; ++j)
#pragma unroll
      for (int r = 0; r < 4; ++r)
        s[j][r] *= 0.125f;

    float tm = s[0][0];
#pragma unroll
    for (int j = 0; j < 8; ++j)
#pragma unroll
      for (int r = 0; r < 4; ++r)
        tm = fmaxf(tm, s[j][r]);
    tm = fmaxf(tm, __shfl_xor(tm, 16));
    tm = fmaxf(tm, __shfl_xor(tm, 32));
    // defer-max: if no lane grew past mr+8, keep mr (alpha=1, skip O-rescale)
    bool defer = (bool)__all(tm <= mr + 8.0f);
    float alpha = 1.0f;
    if (!defer) {
      float mnew = fmaxf(mr, tm);
      alpha = __expf(mr - mnew);
      mr = mnew;
    }
    float ps = 0.f;
#pragma unroll
    for (int j = 0; j < 8; ++j) {
      float p0 = __expf(s[j][0] - mr);
      float p1 = __expf(s[j][1] - mr);
      float p2 = __expf(s[j][2] - mr);
      float p3 = __expf(s[j][3] - mr);
      ps += (p0 + p1) + (p2 + p3);
      unsigned int lo = cvt_pk_bf16(p0, p1);
      unsigned int hi = cvt_pk_bf16(p2, p3);
      *(uint2*)&Pw[col * 136 + j * 16 + quad * 4] = (uint2){lo, hi};
    }
    ps += __shfl_xor(ps, 16);
    ps += __shfl_xor(ps, 32);
    lr = lr * alpha + ps;

    if (!defer) {
      // broadcast alpha to O's q-rows (rows = quad*4+r, alpha lives at lane q)
      float a0 = __shfl(alpha, quad * 4 + 0);
      float a1 = __shfl(alpha, quad * 4 + 1);
      float a2 = __shfl(alpha, quad * 4 + 2);
      float a3 = __shfl(alpha, quad * 4 + 3);
#pragma unroll
      for (int n = 0; n < 4; ++n) {
        O[n][0] *= a0; O[n][1] *= a1; O[n][2] *= a2; O[n][3] *= a3;
      }
    }
#pragma unroll
    for (int kk = 0; kk < 4; ++kk) {
      s16x8 aP = *(const s16x8*)&Pw[col * 136 + kk * 32 + quad * 8];
#pragma unroll
      for (int n = 0; n < 4; ++n) {
        s16x8 bV = *(const s16x8*)&Vl[(n * 16 + col) * 136 + kk * 32 + quad * 8];
        O[n] = __builtin_amdgcn_mfma_f32_16x16x32_bf16(aP, bV, O[n], 0, 0, 0);
      }
    }
  }

#pragma unroll
  for (int r = 0; r < 4; ++r) {
    int q = qt * 64 + w * 16 + quad * 4 + r;
    long gq = (long)bh * SLQ + q;
#pragma unroll
    for (int n = 0; n < 4; ++n)
      Opart[(gq * 4 + ck) * 64 + n * 16 + col] = f2bf(O[n][r]);
  }
  if (quad == 0) {
    int q = qt * 64 + w * 16 + col;
    ml[((long)bh * SLQ + q) * 4 + ck] = (float2){mr, lr};
  }
}

// merge 4 cross chunks -> attn; also emit global (M, L) stats for the weights pass
__global__ __launch_bounds__(256)
void cross_combine(const u16* __restrict__ Opart, const float2* __restrict__ ml,
                   u16* __restrict__ attn, float2* __restrict__ stat,
                   const int* __restrict__ qlen)
{
  int gr = blockIdx.x * 16 + (threadIdx.x >> 4);
  int bh = gr >> 10, q = gr & 1023;
  int b = bh >> 3, h = bh & 7;
  if (q >= qlen[b]) return;
  int d = (threadIdx.x & 15) * 4;
  long base = (long)gr * 4;
  float M = -1e30f;
#pragma unroll
  for (int c = 0; c < 4; ++c) M = fmaxf(M, ml[base + c].x);
  float L = 0.f;
  float ax = 0.f, ay = 0.f, az = 0.f, aw = 0.f;
#pragma unroll
  for (int c = 0; c < 4; ++c) {
    float2 st = ml[base + c];
    float wgt = __expf(st.x - M);
    L += st.y * wgt;
    const u16* p = Opart + (base + c) * 64 + d;
    ax += bf2f(p[0]) * wgt; ay += bf2f(p[1]) * wgt;
    az += bf2f(p[2]) * wgt; aw += bf2f(p[3]) * wgt;
  }
  if (d == 0) stat[gr] = (float2){M, L};
  float inv = 1.0f / L;
  unsigned int lo = cvt_pk_bf16(ax * inv, ay * inv);
  unsigned int hi = cvt_pk_bf16(az * inv, aw * inv);
  *(uint2*)&attn[((long)b * SLQ + q) * EE + h * HD + d] = (uint2){lo, hi};
}

// head-mean attention weights by QK^T recompute.
// block = (key tile of 128, q tile of 64, b); K staged in LDS per head,
// software-pipelined over heads; wave owns 16 q rows x 128 keys.
__global__ __launch_bounds__(256, 4)
void wmean_recompute(const u16* __restrict__ Qc, const u16* __restrict__ Kc,
                     const float2* __restrict__ stat, float* __restrict__ outw,
                     const int* __restrict__ qlen)
{
  const int kt = blockIdx.x;             // 16 key tiles of 128
  const int qt = blockIdx.y;             // 16 q tiles of 64
  const int b  = blockIdx.z;             // 4
  const int qn = qlen[b];
  const int q0 = qt * 64;
  const int t = threadIdx.x, lane = t & 63, w = t >> 6;
  const int col = lane & 15, quad = lane >> 4;

  float* wr = outw + ((long)b * SLQ + q0) * SLK + kt * 128;

  if (q0 >= qn) {
    float4 z = {0.f, 0.f, 0.f, 0.f};
    for (int i = t; i < 64 * 32; i += 256) {
      int row = i >> 5, c = (i & 31) << 2;
      *(float4*)&wr[(long)row * SLK + c] = z;
    }
    return;
  }

  __shared__ __align__(16) u16 Kl[128 * 72];

  const int qw = q0 + w * 16;            // wave's 16 q rows
  const u16* Kbase = Kc + ((long)b * HH * SLK + (long)kt * 128) * HD;

  const int krow = t >> 3, kcol = (t & 7) * 8;

  // preload head 0's K tile into NAMED registers
  uint4 kr0, kr1, kr2, kr3;
  kr0 = *(const uint4*)(Kbase + (long)(krow) * HD + kcol);
  kr1 = *(const uint4*)(Kbase + (long)(krow + 32) * HD + kcol);
  kr2 = *(const uint4*)(Kbase + (long)(krow + 64) * HD + kcol);
  kr3 = *(const uint4*)(Kbase + (long)(krow + 96) * HD + kcol);

  f32x4 acc[8];
#pragma unroll
  for (int j = 0; j < 8; ++j) acc[j] = (f32x4){0.f, 0.f, 0.f, 0.f};

#pragma unroll 1
  for (int h = 0; h < 8; ++h) {
    const int bh = b * 8 + h;
    __syncthreads();                     // previous iteration's LDS reads done
    *(uint4*)&Kl[(krow) * 72 + kcol] = kr0;
    *(uint4*)&Kl[(krow + 32) * 72 + kcol] = kr1;
    *(uint4*)&Kl[(krow + 64) * 72 + kcol] = kr2;
    *(uint4*)&Kl[(krow + 96) * 72 + kcol] = kr3;
    if (h < 7) {
      const u16* Kn = Kbase + (long)(h + 1) * SLK * HD;
      kr0 = *(const uint4*)(Kn + (long)(krow) * HD + kcol);
      kr1 = *(const uint4*)(Kn + (long)(krow + 32) * HD + kcol);
      kr2 = *(const uint4*)(Kn + (long)(krow + 64) * HD + kcol);
      kr3 = *(const uint4*)(Kn + (long)(krow + 96) * HD + kcol);
    }
    const u16* Qb = Qc + ((long)bh * SLQ + qw) * HD;
    s16x8 aQ0 = *(const s16x8*)(Qb + col * HD + quad * 8);
    s16x8 aQ1 = *(const s16x8*)(Qb + col * HD + 32 + quad * 8);
    float m_[4], il_[4];
#pragma unroll
    for (int r = 0; r < 4; ++r) {
      float2 st = stat[(long)bh * SLQ + qw + quad * 4 + r];
      m_[r] = st.x; il_[r] = 0.125f / st.y;
    }
    __syncthreads();                     // K tile visible

    f32x4 s[8];
#pragma unroll
    for (int j = 0; j < 8; ++j) s[j] = (f32x4){0.f, 0.f, 0.f, 0.f};
#pragma unroll
    for (int j = 0; j < 8; ++j) {
      s16x8 bK0 = *(const s16x8*)&Kl[(j * 16 + col) * 72 + quad * 8];
      s16x8 bK1 = *(const s16x8*)&Kl[(j * 16 + col) * 72 + 32 + quad * 8];
      s[j] = __builtin_amdgcn_mfma_f32_16x16x32_bf16(aQ0, bK0, s[j], 0, 0, 0);
      s[j] = __builtin_amdgcn_mfma_f32_16x16x32_bf16(aQ1, bK1, s[j], 0, 0, 0);
    }
#pragma unroll
    for (int j = 0; j < 8; ++j)
#pragma unroll
      for (int r = 0; r < 4; ++r)
        acc[j][r] += __expf(s[j][r] * 0.125f - m_[r]) * il_[r];
  }

#pragma unroll
  for (int r = 0; r < 4; ++r) {
    int row = w * 16 + quad * 4 + r;
    bool v = (q0 + row) < qn;
#pragma unroll
    for (int j = 0; j < 8; ++j)
      wr[(long)row * SLK + j * 16 + col] = v ? acc[j][r] : 0.f;
  }
}

// self-attention: chunk of 256 keys per block (2 tiles, online softmax), bf16 partials.
// SWAPPED QK^T; defer-max; cvt_pk P-store. 1-D grid, XCD-swizzled; named-reg prefetch.
__global__ __launch_bounds__(256, 3)
void self_flash_chunk(const u16* __restrict__ Qc, const u16* __restrict__ Kc,
                      const u16* __restrict__ Vt, u16* __restrict__ Opart,
                      float2* __restrict__ ml, const int* __restrict__ qlen)
{
  const int lin = blockIdx.x;
  const int lid = (lin & 7) * 256 + (lin >> 3);   // bijective: 2048 % 8 == 0
  const int qt = lid & 15;
  const int bh = (lid >> 4) & 31;
  const int ck = lid >> 9;               // 4 chunks of 256
  const int b = bh >> 3;
  const int kmax = qlen[b];
  if (qt * 64 >= kmax || ck * 256 >= kmax) return;

  __shared__ __align__(16) u16 Kt[128 * 72];
  __shared__ __align__(16) u16 Vl[64 * 136];
  __shared__ __align__(16) u16 Pl[4 * 16 * 136];

  const int t = threadIdx.x, lane = t & 63, w = t >> 6;
  const int col = lane & 15, quad = lane >> 4;

  const u16* Qb = Qc + (long)bh * SLQ * HD;
  const u16* Kb = Kc + (long)bh * SLQ * HD;
  const u16* Vb = Vt + (long)bh * HD * SLQ;

  s16x8 aQ[2];
#pragma unroll
  for (int kk = 0; kk < 2; ++kk)
    aQ[kk] = *(const s16x8*)(Qb + (long)(qt * 64 + w * 16 + col) * HD + kk * 32 + quad * 8);

  f32x4 O[4];
#pragma unroll
  for (int n = 0; n < 4; ++n) O[n] = (f32x4){0.f, 0.f, 0.f, 0.f};
  float mr = -1e30f, lr = 0.f;

  u16* Pw = Pl + w * 16 * 136;

  const int krow = t >> 3, kcol = (t & 7) * 8;
  const int vrow = t >> 4, vcol = (t & 15) * 8;

  // prologue: prefetch tile 0 (always within buffer; max addr < SLQ)
  uint4 kr0, kr1, kr2, kr3, vr0, vr1, vr2, vr3;
  {
    const int kb = ck * 256;
    kr0 = *(const uint4*)(Kb + (long)(kb + krow) * HD + kcol);
    kr1 = *(const uint4*)(Kb + (long)(kb + krow + 32) * HD + kcol);
    kr2 = *(const uint4*)(Kb + (long)(kb + krow + 64) * HD + kcol);
    kr3 = *(const uint4*)(Kb + (long)(kb + krow + 96) * HD + kcol);
    vr0 = *(const uint4*)(Vb + (long)(vrow) * SLQ + kb + vcol);
    vr1 = *(const uint4*)(Vb + (long)(vrow + 16) * SLQ + kb + vcol);
    vr2 = *(const uint4*)(Vb + (long)(vrow + 32) * SLQ + kb + vcol);
    vr3 = *(const uint4*)(Vb + (long)(vrow + 48) * SLQ + kb + vcol);
  }

#pragma unroll
  for (int kt = 0; kt < 2; ++kt) {
    const int k0 = ck * 256 + kt * 128;
    if (k0 >= kmax) break;               // block-uniform
    __syncthreads();
    *(uint4*)&Kt[(krow) * 72 + kcol] = kr0;
    *(uint4*)&Kt[(krow + 32) * 72 + kcol] = kr1;
    *(uint4*)&Kt[(krow + 64) * 72 + kcol] = kr2;
    *(uint4*)&Kt[(krow + 96) * 72 + kcol] = kr3;
    *(uint4*)&Vl[(vrow) * 136 + vcol] = vr0;
    *(uint4*)&Vl[(vrow + 16) * 136 + vcol] = vr1;
    *(uint4*)&Vl[(vrow + 32) * 136 + vcol] = vr2;
    *(uint4*)&Vl[(vrow + 48) * 136 + vcol] = vr3;
    if (kt < 1) {
      const int kb = ck * 256 + 128;     // in-bounds (max 896+127 < 1024)
      kr0 = *(const uint4*)(Kb + (long)(kb + krow) * HD + kcol);
      kr1 = *(const uint4*)(Kb + (long)(kb + krow + 32) * HD + kcol);
      kr2 = *(const uint4*)(Kb + (long)(kb + krow + 64) * HD + kcol);
      kr3 = *(const uint4*)(Kb + (long)(kb + krow + 96) * HD + kcol);
      vr0 = *(const uint4*)(Vb + (long)(vrow) * SLQ + kb + vcol);
      vr1 = *(const uint4*)(Vb + (long)(vrow + 16) * SLQ + kb + vcol);
      vr2 = *(const uint4*)(Vb + (long)(vrow + 32) * SLQ + kb + vcol);
      vr3 = *(const uint4*)(Vb + (long)(vrow + 48) * SLQ + kb + vcol);
    }
    __syncthreads();

    // s[j][r] = S[k = k0 + j*16 + quad*4 + r][q = col]
    f32x4 s[8];
#pragma unroll
    for (int j = 0; j < 8; ++j) s[j] = (f32x4){0.f, 0.f, 0.f, 0.f};
#pragma unroll
    for (int j = 0; j < 8; ++j)
#pragma unroll
      for (int kk = 0; kk < 2; ++kk) {
        s16x8 bK = *(const s16x8*)&Kt[(j * 16 + col) * 72 + kk * 32 + quad * 8];
        s[j] = __builtin_amdgcn_mfma_f32_16x16x32_bf16(bK, aQ[kk], s[j], 0, 0, 0);
      }
#pragma unroll
    for (int j = 0; j < 8; ++j)
#pragma unroll
      for (int r = 0; r < 4; ++r) {
        bool ok = (k0 + j * 16 + quad * 4 + r) < kmax;
        s[j][r] = ok ? s[j][r] * 0.125f : -1e30f;
      }

    float tm = s[0][0];
#pragma unroll
    for (int j = 0; j < 8; ++j)
#pragma unroll
      for (int r = 0; r < 4; ++r)
        tm = fmaxf(tm, s[j][r]);
    tm = fmaxf(tm, __shfl_xor(tm, 16));
    tm = fmaxf(tm, __shfl_xor(tm, 32));
    bool defer = (bool)__all(tm <= mr + 8.0f);
    float alpha = 1.0f;
    if (!defer) {
      float mnew = fmaxf(mr, tm);
      alpha = __expf(mr - mnew);
      mr = mnew;
    }
    float ps = 0.f;
#pragma unroll
    for (int j = 0; j < 8; ++j) {
      float p0 = __expf(s[j][0] - mr);
      float p1 = __expf(s[j][1] - mr);
      float p2 = __expf(s[j][2] - mr);
      float p3 = __expf(s[j][3] - mr);
      ps += (p0 + p1) + (p2 + p3);
      unsigned int lo = cvt_pk_bf16(p0, p1);
      unsigned int hi = cvt_pk_bf16(p2, p3);
      *(uint2*)&Pw[col * 136 + j * 16 + quad * 4] = (uint2){lo, hi};
    }
    ps += __shfl_xor(ps, 16);
    ps += __shfl_xor(ps, 32);
    lr = lr * alpha + ps;

    if (!defer) {
      float a0 = __shfl(alpha, quad * 4 + 0);
      float a1 = __shfl(alpha, quad * 4 + 1);
      float a2 = __shfl(alpha, quad * 4 + 2);
      float a3 = __shfl(alpha, quad * 4 + 3);
#pragma unroll
      for (int n = 0; n < 4; ++n) {
        O[n][0] *= a0; O[n][1] *= a1; O[n][2] *= a2; O[n][3] *= a3;
      }
    }
#pragma unroll
    for (int kk = 0; kk < 4; ++kk) {
      s16x8 aP = *(const s16x8*)&Pw[col * 136 + kk * 32 + quad * 8];
#pragma unroll
      for (int n = 0; n < 4; ++n) {
        s16x8 bV = *(const s16x8*)&Vl[(n * 16 + col) * 136 + kk * 32 + quad * 8];
        O[n] = __builtin_amdgcn_mfma_f32_16x16x32_bf16(aP, bV, O[n], 0, 0, 0);
      }
    }
  }

#pragma unroll
  for (int r = 0; r < 4; ++r) {
    int q = qt * 64 + w * 16 + quad * 4 + r;
    long gq = (long)bh * SLQ + q;
#pragma unroll
    for (int n = 0; n < 4; ++n)
      Opart[(gq * 4 + ck) * 64 + n * 16 + col] = f2bf(O[n][r]);
  }
  if (quad == 0) {
    int q = qt * 64 + w * 16 + col;
    ml[((long)bh * SLQ + q) * 4 + ck] = (float2){mr, lr};
  }
}

__global__ __launch_bounds__(256)
void self_combine(const u16* __restrict__ Opart, const float2* __restrict__ ml,
                  u16* __restrict__ attn, const int* __restrict__ qlen)
{
  int gr = blockIdx.x * 16 + (threadIdx.x >> 4);
  int bh = gr >> 10, q = gr & 1023;
  int b = bh >> 3, h = bh & 7;
  int kmax = qlen[b];
  if (q >= kmax) return;
  int NC = (kmax + 255) >> 8;
  int d = (threadIdx.x & 15) * 4;
  long base = (long)gr * 4;
  float M = -1e30f;
  for (int c = 0; c < NC; ++c) M = fmaxf(M, ml[base + c].x);
  float L = 0.f;
  float ax = 0.f, ay = 0.f, az = 0.f, aw = 0.f;
  for (int c = 0; c < NC; ++c) {
    float2 st = ml[base + c];
    float wgt = __expf(st.x - M);
    L += st.y * wgt;
    const u16* p = Opart + (base + c) * 64 + d;
    ax += bf2f(p[0]) * wgt; ay += bf2f(p[1]) * wgt;
    az += bf2f(p[2]) * wgt; aw += bf2f(p[3]) * wgt;
  }
  float inv = 1.0f / L;
  unsigned int lo = cvt_pk_bf16(ax * inv, ay * inv);
  unsigned int hi = cvt_pk_bf16(az * inv, aw * inv);
  *(uint2*)&attn[((long)b * SLQ + q) * EE + h * HD + d] = (uint2){lo, hi};
}

// fused input conversion: masked queries + keys + 9 weight matrices
__global__ __launch_bounds__(256)
void cvt_all(const float* __restrict__ queries, const float* __restrict__ keys,
             const int* __restrict__ qlen,
             const float* w0, const float* w1, const float* w2, const float* w3,
             const float* w4, const float* w5, const float* w6, const float* w7,
             const float* w8,
             u16* __restrict__ q0, u16* __restrict__ keysb, u16* __restrict__ Wb) {
  int blk = blockIdx.x;
  int t = threadIdx.x;
  const float* src;
  u16* dst;
  long off;
  bool mask = false;
  int b = 0, q = 0;
  if (blk < 1024) {
    off = (long)blk * 2048 + t * 8;
    int row = (int)(off >> 9);
    b = row >> 10; q = row & 1023;
    mask = true;
    src = queries; dst = q0;
  } else if (blk < 3072) {
    off = (long)(blk - 1024) * 2048 + t * 8;
    src = keys; dst = keysb;
  } else {
    int mat = (blk - 3072) >> 7, part = (blk - 3072) & 127;
    const float* srcs[9] = {w0, w1, w2, w3, w4, w5, w6, w7, w8};
    src = srcs[mat];
    off = (long)part * 2048 + t * 8;
    dst = Wb + (long)mat * EE * EE;
  }
  s16x8 o = (s16x8){0, 0, 0, 0, 0, 0, 0, 0};
  if (!mask || q < qlen[b]) {
    float4 a = *(const float4*)&src[off];
    float4 c = *(const float4*)&src[off + 4];
    o[0] = (short)f2bf(a.x); o[1] = (short)f2bf(a.y);
    o[2] = (short)f2bf(a.z); o[3] = (short)f2bf(a.w);
    o[4] = (short)f2bf(c.x); o[5] = (short)f2bf(c.y);
    o[6] = (short)f2bf(c.z); o[7] = (short)f2bf(c.w);
  }
  *(s16x8*)&dst[off] = o;
}

__device__ __forceinline__ float blockSum(float v, float* red4) {
#pragma unroll
  for (int o = 32; o; o >>= 1) v += __shfl_xor(v, o);
  if ((threadIdx.x & 63) == 0) red4[threadIdx.x >> 6] = v;
  __syncthreads();
  v = red4[0] + red4[1] + red4[2] + red4[3];
  __syncthreads();
  return v;
}

template<int OUTF32>
__global__ __launch_bounds__(256)
void silu_ln_kernel(const u16* __restrict__ x1, const u16* __restrict__ x2,
                    const float* __restrict__ g, const float* __restrict__ beta,
                    const int* __restrict__ qlen, void* __restrict__ outv, int mode) {
  int row = blockIdx.x;
  int b = row >> 10, q = row & 1023;
  int t = threadIdx.x;
  if (mode && q >= qlen[b]) {
    if (mode == 1) {
      if (OUTF32) {
        float* o = (float*)outv + (long)row * EE;
        o[2 * t] = 0.f; o[2 * t + 1] = 0.f;
      } else {
        u16* o = (u16*)outv + (long)row * EE;
        *(unsigned int*)&o[2 * t] = 0u;
      }
    }
    return;
  }
  __shared__ float red4[4];
  const u16* p1 = x1 + (long)row * EE;
  const u16* p2 = x2 + (long)row * EE;
  float a0 = bf2f(p1[2 * t]) + bf2f(p2[2 * t]);
  float a1 = bf2f(p1[2 * t + 1]) + bf2f(p2[2 * t + 1]);
  a0 = a0 / (1.f + __expf(-a0));
  a1 = a1 / (1.f + __expf(-a1));
  float mu = blockSum(a0 + a1, red4) * (1.f / 512.f);
  float d0 = a0 - mu, d1 = a1 - mu;
  float var = blockSum(d0 * d0 + d1 * d1, red4) * (1.f / 512.f);
  float rs = rsqrtf(var + 1e-5f);
  float r0 = d0 * rs * g[2 * t] + beta[2 * t];
  float r1 = d1 * rs * g[2 * t + 1] + beta[2 * t + 1];
  if (OUTF32) {
    float* o = (float*)outv + (long)row * EE;
    o[2 * t] = r0; o[2 * t + 1] = r1;
  } else {
    u16* o = (u16*)outv + (long)row * EE;
    o[2 * t] = f2bf(r0); o[2 * t + 1] = f2bf(r1);
  }
}

extern "C" void kernel_launch(void* const* d_in, const int* in_sizes, int n_in,
                              void* d_out, int out_size, void* d_ws, size_t ws_size,
                              hipStream_t stream) {
  const float* queries = (const float*)d_in[0];
  const float* keys    = (const float*)d_in[1];
  const int*   qlen    = (const int*)d_in[2];
  const float* cWq = (const float*)d_in[3],  *cbq = (const float*)d_in[4];
  const float* cWk = (const float*)d_in[5],  *cbk = (const float*)d_in[6];
  const float* cWv = (const float*)d_in[7],  *cbv = (const float*)d_in[8];
  const float* cWo = (const float*)d_in[9],  *cbo = (const float*)d_in[10];
  const float* sWq = (const float*)d_in[11], *sbq = (const float*)d_in[12];
  const float* sWk = (const float*)d_in[13], *sbk = (const float*)d_in[14];
  const float* sWv = (const float*)d_in[15], *sbv = (const float*)d_in[16];
  const float* sWo = (const float*)d_in[17], *sbo = (const float*)d_in[18];
  const float* Wf  = (const float*)d_in[19], *bfb = (const float*)d_in[20];
  const float* g_cross = (const float*)d_in[21], *b_cross = (const float*)d_in[22];
  const float* g_ffn   = (const float*)d_in[23], *b_ffn   = (const float*)d_in[24];
  const float* g_self  = (const float*)d_in[25], *b_self  = (const float*)d_in[26];

  float* out_q = (float*)d_out;
  float* out_w = out_q + (long)BB * SLQ * EE;

  u16* ws = (u16*)d_ws;
  u16* S     = ws;                               // region kept for layout; cross S no longer materialized
  u16* Qc    = S   + (long)BB * HH * SLQ * SLK;
  u16* Kc    = Qc  + (long)BB * HH * SLQ * HD;
  u16* Vt    = Kc  + (long)BB * HH * SLK * HD;
  u16* q0    = Vt  + (long)BB * HH * SLK * HD;
  u16* keysb = q0  + (long)BB * SLQ * EE;
  u16* attn  = keysb + (long)BB * SLK * EE;
  u16* proj  = attn + (long)BB * SLQ * EE;
  u16* q1    = proj + (long)BB * SLQ * EE;
  u16* fbuf  = q1  + (long)BB * SLQ * EE;
  u16* q2    = fbuf + (long)BB * SLQ * EE;
  u16* Wb    = q2  + (long)BB * SLQ * EE;
  const long WSLOT = (long)EE * EE;
  u16*    Cpb  = Wb + 9 * WSLOT;                  // cross O partials bf16: 32768*4*64
  float2* stat = (float2*)(Cpb + 8388608);        // 32768 float2 (M, L)

  // cross flash ml lives in the (now dead) S region, clear of the self overlay below
  float2* mlC = (float2*)(S + 33554432);          // 32768*4 float2

  // self partials overlay S (front of region)
  u16*    OpS = S;                                // 32768*4*64 bf16
  float2* mlS = (float2*)(S + 8388608);           // 32768*4 float2

  u16* bWq = Wb + 0 * WSLOT; u16* bWk = Wb + 1 * WSLOT; u16* bWv = Wb + 2 * WSLOT;
  u16* bWo = Wb + 3 * WSLOT; u16* bsWq = Wb + 4 * WSLOT; u16* bsWk = Wb + 5 * WSLOT;
  u16* bsWv = Wb + 6 * WSLOT; u16* bsWo = Wb + 7 * WSLOT; u16* bWf = Wb + 8 * WSLOT;

  dim3 blk(256);
  const int MQ = BB * SLQ;   // 4096
  const int MK = BB * SLK;   // 8192

  cvt_all<<<dim3(3072 + 9 * 128), blk, 0, stream>>>(
      queries, keys, qlen, cWq, cWk, cWv, cWo, sWq, sWk, sWv, sWo, Wf, q0, keysb, Wb);

  // cross Q projection (64^2: qlen-skip leaves ~288 of 512 blocks -> keep small tile)
  gemm_nt<64, 64, 1, 2><<<dim3(EE / 64, MQ / 64, 1), blk, 0, stream>>>(
      q0, bWq, cbq, Qc, MQ, EE, EE, EE, EE, 0, 0, 0, 0, 1.0f, SLQ, qlen);
  // cross K+V projections in one dispatch (128x64: no skip, 1024 blocks)
  gemm_proj<128, 64, 0, 2><<<dim3(EE / 64, MK / 128, 2), blk, 0, stream>>>(
      keysb, bWk, bWv, nullptr, cbk, cbv, nullptr, Kc, Vt, nullptr, MK, EE, SLK, qlen);

  // fused cross attention: no S materialization (1-D swizzled grid)
  cross_flash_chunk<<<dim3(2048), blk, 0, stream>>>(Qc, Kc, Vt, Cpb, mlC, qlen);
  cross_combine<<<dim3(2048), blk, 0, stream>>>(Cpb, mlC, attn, stat, qlen);
  // head-mean attention weights via QK^T recompute (LDS-staged, head-pipelined)
  wmean_recompute<<<dim3(16, 16, BB), blk, 0, stream>>>(Qc, Kc, stat, out_w, qlen);

  gemm_nt<64, 64, 0, 2><<<dim3(EE / 64, MQ / 64, 1), blk, 0, stream>>>(
      attn, bWo, cbo, proj, MQ, EE, EE, EE, EE, EE, 0, 0, 0, 1.0f, SLQ, qlen);

  silu_ln_kernel<0><<<dim3(MQ), blk, 0, stream>>>(proj, q0, g_cross, b_cross, qlen, q1, 2);

  gemm_nt<64, 64, 0, 2><<<dim3(EE / 64, MQ / 64, 1), blk, 0, stream>>>(
      q1, bWf, bfb, fbuf, MQ, EE, EE, EE, EE, EE, 0, 0, 0, 1.0f, SLQ, qlen);

  silu_ln_kernel<0><<<dim3(MQ), blk, 0, stream>>>(q1, fbuf, g_ffn, b_ffn, qlen, q2, 1);

  // self Q/K/V projections in one dispatch (128x64: ~432 surviving blocks)
  gemm_proj<128, 64, 2, 3><<<dim3(EE / 64, MQ / 128, 3), blk, 0, stream>>>(
      q2, bsWq, bsWk, bsWv, sbq, sbk, sbv, Qc, Kc, Vt, MQ, EE, SLQ, qlen);

  // fused self attention (partials overlay S; 1-D swizzled grid)
  self_flash_chunk<<<dim3(2048), blk, 0, stream>>>(Qc, Kc, Vt, OpS, mlS, qlen);
  self_combine<<<dim3(2048), blk, 0, stream>>>(OpS, mlS, attn, qlen);

  gemm_nt<64, 64, 0, 2><<<dim3(EE / 64, MQ / 64, 1), blk, 0, stream>>>(
      attn, bsWo, sbo, proj, MQ, EE, EE, EE, EE, EE, 0, 0, 0, 1.0f, SLQ, qlen);

  silu_ln_kernel<1><<<dim3(MQ), blk, 0, stream>>>(q2, proj, g_self, b_self, qlen, out_q, 1);
}